// Round 1
// 1740.071 us; speedup vs baseline: 1.1186x; 1.1186x over previous
//
#include <hip/hip_runtime.h>
#include <hip/hip_bf16.h>
#include <cstdint>
#include <cstddef>

#define N_G 50000
#define N_D 20000
#define E_G 300000
#define E_D 150000
#define BATCH 65536

typedef _Float16 f16;
typedef _Float16 f16x8 __attribute__((ext_vector_type(8)));
typedef _Float16 f16x4 __attribute__((ext_vector_type(4)));
typedef float f32x4 __attribute__((ext_vector_type(4)));

__device__ __forceinline__ float clampf(float v) {
    return fminf(fmaxf(v, -60000.f), 60000.f);  // also squashes NaN
}

__device__ __forceinline__ void gl_lds16(const void* g, void* l) {
    __builtin_amdgcn_global_load_lds(
        (const __attribute__((address_space(1))) unsigned int*)g,
        (__attribute__((address_space(3))) unsigned int*)l, 16, 0, 0);
}

// ---------------- GEMM: C[M,N] = act(A[M,K] @ Bt[N,K]^T + bias) ----------------
// R7 structure (known-good): 128x128 tile, BK=64, 4 waves (2x2), 256 threads.
// - global_load_lds width-16 staging
// - XOR chunk swizzle -> 0 LDS bank conflicts (verified R6)
// - XCD-aware block remap (FETCH 266->66 MB verified R6)
// - optional fused pair-gather (bidx != null)
// - optional fused final linear (W4 != null): out[row] += lrelu(C_tile) @ W4 via atomics
// R8: vectorized epilogue — per-wave LDS transpose (XOR-swizzled, conflict-free),
//     then f16x8 coalesced stores (was: 64x 2-byte scalar stores per thread).
__global__ __launch_bounds__(256) void gemm_f16(
    const f16* __restrict__ A,
    const int* __restrict__ bidx,
    const f16* __restrict__ geneT, const f16* __restrict__ disT, int rowBase,
    const f16* __restrict__ Bt, const float* __restrict__ bias,
    f16* __restrict__ C, int M, int N, int K, int relu, int CB, int RB,
    const float* __restrict__ W4, float* __restrict__ outF)
{
    alignas(16) __shared__ f16 sA[128 * 64];
    alignas(16) __shared__ f16 sB[128 * 64];
    const int t = threadIdx.x;
    const int w = t >> 6, l = t & 63;
    const int wm = w >> 1, wn = w & 1;
    const int q = l >> 4, lr = l & 15;

    // XCD-aware remap (dispatch round-robins consecutive IDs across 8 XCDs)
    int flat = blockIdx.x;
    int cb, rb;
    if ((RB & 7) == 0) {
        int x = flat & 7, idx = flat >> 3;
        int Sx = RB >> 3;
        cb = idx % CB;
        rb = x * Sx + idx / CB;
    } else {
        cb = flat % CB;
        rb = flat / CB;
    }
    const int mBase = rb * 128, nBase = cb * 128;

    // staging: load j covers seg=j*4+w, LDS rows [seg*8, seg*8+8); lane -> (subrow, chunk)
    const int subrow = l >> 3;   // 0..7
    const int c = l & 7;         // 16B chunk 0..7 within a 128B row
    const char* pA[4];
    const char* pD[4];
    const char* pB[4];
    const bool fused = (bidx != nullptr);
#pragma unroll
    for (int j = 0; j < 4; j++) {
        int seg = j * 4 + w;
        int lrow = seg * 8 + subrow;               // 0..127
        int coff = ((c ^ (lrow & 7)) << 4);        // swizzled chunk byte offset
        if (fused) {
            int rg = rowBase + mBase + lrow;       // M % 128 == 0 on this path
            int gi = bidx[2 * rg], di = bidx[2 * rg + 1];
            pA[j] = (const char*)geneT + (size_t)gi * 512 + coff;
            pD[j] = (const char*)disT + (size_t)di * 512 + coff;
        } else {
            int arow = mBase + lrow; if (arow > M - 1) arow = M - 1;
            pA[j] = (const char*)A + (size_t)arow * K * 2 + coff;
            pD[j] = nullptr;
        }
        int brow = nBase + lrow; if (brow > N - 1) brow = N - 1;
        pB[j] = (const char*)Bt + (size_t)brow * K * 2 + coff;
    }

    f32x4 acc[4][4] = {};

    for (int k0 = 0; k0 < K; k0 += 64) {
        __syncthreads();   // prev iter's LDS reads done
#pragma unroll
        for (int j = 0; j < 4; j++) {
            int seg = j * 4 + w;
            const char* srcA;
            if (fused)
                srcA = (k0 < 256) ? (pA[j] + (size_t)k0 * 2) : (pD[j] + (size_t)(k0 - 256) * 2);
            else
                srcA = pA[j] + (size_t)k0 * 2;
            gl_lds16(srcA, sA + seg * 512);
            gl_lds16(pB[j] + (size_t)k0 * 2, sB + seg * 512);
        }
        __syncthreads();   // drain staging
        f16x8 a0[4], a1[4], b0[4], b1[4];
#pragma unroll
        for (int i = 0; i < 4; i++) {
            int r = wm * 64 + i * 16 + lr;
            int rs = r * 64;
            int x0 = (q ^ (r & 7)) << 3;
            int x1 = ((4 + q) ^ (r & 7)) << 3;
            a0[i] = *(const f16x8*)(sA + rs + x0);
            a1[i] = *(const f16x8*)(sA + rs + x1);
        }
#pragma unroll
        for (int jj = 0; jj < 4; jj++) {
            int r = wn * 64 + jj * 16 + lr;
            int rs = r * 64;
            int x0 = (q ^ (r & 7)) << 3;
            int x1 = ((4 + q) ^ (r & 7)) << 3;
            b0[jj] = *(const f16x8*)(sB + rs + x0);
            b1[jj] = *(const f16x8*)(sB + rs + x1);
        }
#pragma unroll
        for (int i = 0; i < 4; i++)
#pragma unroll
            for (int jj = 0; jj < 4; jj++) {
                acc[i][jj] = __builtin_amdgcn_mfma_f32_16x16x32_f16(a0[i], b0[jj], acc[i][jj], 0, 0, 0);
                acc[i][jj] = __builtin_amdgcn_mfma_f32_16x16x32_f16(a1[i], b1[jj], acc[i][jj], 0, 0, 0);
            }
    }

    if (W4 != nullptr) {
        // fused final linear: out[rowBase+row] += lrelu(acc + bias) @ W4 (512x2)
        float w40[4], w41[4];
#pragma unroll
        for (int j = 0; j < 4; j++) {
            int col = nBase + wn * 64 + j * 16 + lr;
            w40[j] = W4[col * 2];
            w41[j] = W4[col * 2 + 1];
        }
#pragma unroll
        for (int i = 0; i < 4; i++) {
#pragma unroll
            for (int r = 0; r < 4; r++) {
                int row = mBase + wm * 64 + i * 16 + q * 4 + r;
                float s0 = 0.f, s1 = 0.f;
#pragma unroll
                for (int j = 0; j < 4; j++) {
                    int col = nBase + wn * 64 + j * 16 + lr;
                    float v = acc[i][j][r] + bias[col];
                    v = v >= 0.f ? v : 0.01f * v;
                    v = clampf(v);
                    s0 += v * w40[j];
                    s1 += v * w41[j];
                }
#pragma unroll
                for (int off = 1; off < 16; off <<= 1) {
                    s0 += __shfl_xor(s0, off);
                    s1 += __shfl_xor(s1, off);
                }
                if (lr == 0 && row < M) {
                    atomicAdd(&outF[(size_t)(rowBase + row) * 2], s0);
                    atomicAdd(&outF[(size_t)(rowBase + row) * 2 + 1], s1);
                }
            }
        }
        return;
    }

    // ---- R8 epilogue: per-wave LDS transpose, then coalesced f16x8 stores ----
    // Each wave owns an 8KB slice of the (now idle) staging LDS: a 64x64 f16 tile.
    // Swizzle: col ^ ((row>>2)&3)<<4 ^ (row&3)<<3  -> 2-way on ds_write_b16 (free),
    // 2-way on ds_read_b128 (free). All control flow is block-uniform.
    __syncthreads();   // all waves done reading sA/sB from the K-loop
    f16* lt = ((w >> 1) ? sB : sA) + (w & 1) * 4096;

    float bj[4];
#pragma unroll
    for (int j = 0; j < 4; j++)
        bj[j] = bias ? bias[nBase + wn * 64 + j * 16 + lr] : 0.f;

#pragma unroll
    for (int i = 0; i < 4; i++)
#pragma unroll
        for (int j = 0; j < 4; j++) {
            int col = j * 16 + lr;
#pragma unroll
            for (int r = 0; r < 4; r++) {
                int row = i * 16 + q * 4 + r;       // 0..63 wave-local
                float v = acc[i][j][r] + bj[j];
                if (relu) v = v >= 0.f ? v : 0.01f * v;
                v = clampf(v);
                int cs = col ^ ((((row >> 2) & 3) << 4) ^ ((row & 3) << 3));
                lt[row * 64 + cs] = (f16)v;
            }
        }
    __syncthreads();

    const int rr = l >> 3;      // 0..7: row-within-group
    const int c8 = l & 7;       // 16B chunk within a 128B row
#pragma unroll
    for (int it = 0; it < 8; it++) {
        int row = it * 8 + rr;                      // 0..63 wave-local
        int cs = (c8 * 8) ^ ((((row >> 2) & 3) << 4) ^ ((row & 3) << 3));
        f16x8 vv = *(const f16x8*)(lt + row * 64 + cs);
        int grow = mBase + wm * 64 + row;
        if (grow < M)
            *(f16x8*)(C + (size_t)grow * N + nBase + wn * 64 + c8 * 8) = vv;
    }
}

// ---------------- small kernels ----------------
// R8: vectorized x8 (16B/lane); n is the element count (divisible by 8 here).
__global__ void cvt_f32_f16(const float* __restrict__ in, f16* __restrict__ out, size_t n) {
    size_t i = ((size_t)blockIdx.x * 256 + threadIdx.x) * 8;
    if (i >= n) return;
    f32x4 a = *(const f32x4*)(in + i);
    f32x4 b = *(const f32x4*)(in + i + 4);
    f16x8 o;
    o[0] = (f16)clampf(a.x); o[1] = (f16)clampf(a.y);
    o[2] = (f16)clampf(a.z); o[3] = (f16)clampf(a.w);
    o[4] = (f16)clampf(b.x); o[5] = (f16)clampf(b.y);
    o[6] = (f16)clampf(b.z); o[7] = (f16)clampf(b.w);
    *(f16x8*)(out + i) = o;
}

__global__ void init_out(const float* __restrict__ b4, float* __restrict__ out, int n) {
    int i = blockIdx.x * 256 + threadIdx.x;
    if (i < n) out[i] = b4[i & 1];
}

__global__ void count_deg(const int* __restrict__ ei, int E, int* __restrict__ deg) {
    int e = blockIdx.x * 256 + threadIdx.x;
    if (e < E) atomicAdd(&deg[ei[E + e]], 1);
}

__global__ void scan_deg(const int* __restrict__ deg, int* __restrict__ rowptr, int Nn) {
    __shared__ int part[1024];
    const int t = threadIdx.x;
    const int C = (Nn + 1023) >> 10;
    const int base = t * C;
    int s = 0;
    for (int i = 0; i < C; i++) { int idx = base + i; if (idx < Nn) s += deg[idx]; }
    part[t] = s;
    __syncthreads();
    for (int off = 1; off < 1024; off <<= 1) {
        int v = (t >= off) ? part[t - off] : 0;
        __syncthreads();
        part[t] += v;
        __syncthreads();
    }
    int pre = (t == 0) ? 0 : part[t - 1];
    for (int i = 0; i < C; i++) {
        int idx = base + i;
        if (idx < Nn) { rowptr[idx] = pre; pre += deg[idx]; }
    }
    if (t == 1023) rowptr[Nn] = part[1023];
}

__global__ void fill_csr(const int* __restrict__ ei, int E, const int* __restrict__ rowptr,
                         int* __restrict__ cursor, int* __restrict__ csr) {
    int e = blockIdx.x * 256 + threadIdx.x;
    if (e < E) {
        int d = ei[E + e];
        int p = rowptr[d] + atomicAdd(&cursor[d], 1);
        csr[p] = ei[e];
    }
}

// GraphConv via linearity: PS = X @ [Wr|Ws] (gemm), then per node i:
// y[i] = lrelu( sum_{j->i} P[j] + S[i] + br ).  One wave per node; lane l owns cols l*4..l*4+3.
__global__ void agg_lrelu(const int* __restrict__ rowptr, const int* __restrict__ csr,
                          const f16* __restrict__ PS, const float* __restrict__ br,
                          f16* __restrict__ y, int Nn) {
    int gid = blockIdx.x * 256 + threadIdx.x;
    int node = gid >> 6, l = gid & 63;
    if (node >= Nn) return;
    int beg = rowptr[node], end = rowptr[node + 1];
    f16x4 sv = *(const f16x4*)(PS + (size_t)node * 512 + 256 + l * 4);
    float s0 = (float)sv.x + br[l * 4];
    float s1 = (float)sv.y + br[l * 4 + 1];
    float s2 = (float)sv.z + br[l * 4 + 2];
    float s3 = (float)sv.w + br[l * 4 + 3];
    for (int e = beg; e < end; e++) {
        int src = csr[e];
        f16x4 xv = *(const f16x4*)(PS + (size_t)src * 512 + l * 4);
        s0 += (float)xv.x; s1 += (float)xv.y; s2 += (float)xv.z; s3 += (float)xv.w;
    }
    s0 = s0 >= 0.f ? s0 : 0.01f * s0;
    s1 = s1 >= 0.f ? s1 : 0.01f * s1;
    s2 = s2 >= 0.f ? s2 : 0.01f * s2;
    s3 = s3 >= 0.f ? s3 : 0.01f * s3;
    f16x4 o;
    o.x = (f16)clampf(s0); o.y = (f16)clampf(s1);
    o.z = (f16)clampf(s2); o.w = (f16)clampf(s3);
    *(f16x4*)(y + (size_t)node * 256 + l * 4) = o;
}

// Tiled transpose: WT[dstRowOff + n][k] = W[k][n]; W is K x N fp32, WT rows have length K (f16).
// Coalesced on both sides via 32x33 LDS tile. block (32,8), grid (ceil(N/32), ceil(K/32)).
__global__ void transpose_tile(const float* __restrict__ W, f16* __restrict__ WT,
                               int K, int N, int dstRowOff) {
    __shared__ float tile[32][33];
    int n0 = blockIdx.x * 32, k0 = blockIdx.y * 32;
    int tx = threadIdx.x, ty = threadIdx.y;
    for (int yy = ty; yy < 32; yy += 8) {
        int k = k0 + yy, n = n0 + tx;
        tile[yy][tx] = (k < K && n < N) ? W[(size_t)k * N + n] : 0.f;
    }
    __syncthreads();
    for (int yy = ty; yy < 32; yy += 8) {
        int n = n0 + yy, k = k0 + tx;
        if (n < N && k < K)
            WT[(size_t)(dstRowOff + n) * K + k] = (f16)clampf(tile[tx][yy]);
    }
}

__global__ void colstats(const f16* __restrict__ y, int Nrows, float* __restrict__ stats) {
    int col = threadIdx.x;  // 256
    float s = 0, s2 = 0;
    for (int r = blockIdx.x; r < Nrows; r += gridDim.x) {
        float v = (float)y[(size_t)r * 256 + col];
        s += v; s2 += v * v;
    }
    atomicAdd(&stats[col], s);
    atomicAdd(&stats[256 + col], s2);
}

// BN on y; acc (f16, persistent) += w * BN(y).  R8: vectorized x8.
__global__ void bn_apply(f16* __restrict__ y, const float* __restrict__ stats,
                         const float* __restrict__ g, const float* __restrict__ b,
                         float invN, float w, f16* __restrict__ acc, size_t total) {
    size_t i = ((size_t)blockIdx.x * 256 + threadIdx.x) * 8;
    if (i >= total) return;
    int colb = (int)(i & 255);
    f16x8 yv = *(const f16x8*)(y + i);
    f16x8 av = *(const f16x8*)(acc + i);
    f16x8 yo, ao;
#pragma unroll
    for (int j = 0; j < 8; j++) {
        int col = colb + j;
        float m = stats[col] * invN;
        float var = stats[256 + col] * invN - m * m;
        if (var < 0.f) var = 0.f;
        float rs = 1.0f / sqrtf(var + 1e-5f);
        float v = ((float)yv[j] - m) * rs * g[col] + b[col];
        v = clampf(v);
        yo[j] = (f16)v;
        ao[j] = (f16)clampf((float)av[j] + w * v);
    }
    *(f16x8*)(y + i) = yo;
    *(f16x8*)(acc + i) = ao;
}

extern "C" void kernel_launch(void* const* d_in, const int* in_sizes, int n_in,
                              void* d_out, int out_size, void* d_ws, size_t ws_size,
                              hipStream_t stream) {
    char* ws = (char*)d_ws;
    size_t off = 0;
    auto alloc = [&](size_t bytes) -> void* {
        void* p = ws + off;
        off += (bytes + 255) & ~(size_t)255;
        return p;
    };

    // persistent (~45 MB)
    f16* gene_out = (f16*)alloc((size_t)N_G * 256 * 2);
    f16* dis_out  = (f16*)alloc((size_t)N_D * 256 * 2);
    f16* W1T = (f16*)alloc((size_t)2048 * 512 * 2);
    f16* W2T = (f16*)alloc((size_t)1024 * 2048 * 2);
    f16* W3T = (f16*)alloc((size_t)512 * 1024 * 2);
    f16* WcatT = (f16*)alloc((size_t)512 * 256 * 2);
    int* csr = (int*)alloc((size_t)E_G * 4);
    int* rowptr = (int*)alloc((size_t)(N_G + 1) * 4);
    int* cnt = (int*)alloc((size_t)N_G * 4);
    float* stats = (float*)alloc(512 * 4);

    // scratch: towers use ybA + ybB (25.6 MB each) + PS (51.2 MB); head aliases it
    char* scratch = ws + off;
    size_t avail = (ws_size > off) ? (ws_size - off) : 0;

    f16* ybA = (f16*)scratch;
    f16* ybB = ybA + (size_t)N_G * 256;
    f16* PS  = ybB + (size_t)N_G * 256;   // N_G x 512 f16

    // head chunk: R rows use R*6144 bytes (h1 4KB + h2 2KB per row; h3 fused away)
    int R = BATCH;
    while ((size_t)R * 6144 > avail && R > 256) R >>= 1;
    int chunks = BATCH / R;
    f16* h1 = (f16*)scratch;
    f16* h2 = h1 + (size_t)R * 2048;

    const float* gene_x = (const float*)d_in[0];
    const float* disease_x = (const float*)d_in[1];
    const int* g_ei = (const int*)d_in[2];
    const int* d_ei = (const int*)d_in[3];
    const int* bidx = (const int*)d_in[4];
    float* out = (float*)d_out;

    const float wl[3] = {0.7f, 0.2f, 0.1f};

    auto run_tower = [&](const float* xin, const int* ei, int Nn, int E, int pbase, f16* tout) {
        size_t nelem = (size_t)Nn * 256;
        cvt_f32_f16<<<(int)((nelem / 8 + 255) / 256), 256, 0, stream>>>(xin, ybA, nelem);
        hipMemsetAsync(cnt, 0, (size_t)Nn * 4, stream);
        count_deg<<<(E + 255) / 256, 256, 0, stream>>>(ei, E, cnt);
        scan_deg<<<1, 1024, 0, stream>>>(cnt, rowptr, Nn);
        hipMemsetAsync(cnt, 0, (size_t)Nn * 4, stream);
        fill_csr<<<(E + 255) / 256, 256, 0, stream>>>(ei, E, rowptr, cnt, csr);
        hipMemsetAsync(tout, 0, nelem * 2, stream);
        f16* yin = ybA;
        f16* yout = ybB;
        int RB = (Nn + 127) / 128;
        int RBp = (RB + 7) & ~7;   // R8: pad so the in-kernel XCD remap engages
        for (int l = 0; l < 3; l++) {
            const float* Wr = (const float*)d_in[pbase + l * 5 + 0];
            const float* br = (const float*)d_in[pbase + l * 5 + 1];
            const float* Wss = (const float*)d_in[pbase + l * 5 + 2];
            const float* bg = (const float*)d_in[pbase + l * 5 + 3];
            const float* bb = (const float*)d_in[pbase + l * 5 + 4];
            transpose_tile<<<dim3(8, 8), dim3(32, 8), 0, stream>>>(Wr, WcatT, 256, 256, 0);
            transpose_tile<<<dim3(8, 8), dim3(32, 8), 0, stream>>>(Wss, WcatT, 256, 256, 256);
            // PS = X @ [Wr|Ws]  (M=Nn, N=512, K=256; no bias, no act)
            gemm_f16<<<4 * RBp, 256, 0, stream>>>(yin, nullptr, nullptr, nullptr, 0,
                                                  WcatT, nullptr, PS, Nn, 512, 256, 0, 4, RBp,
                                                  nullptr, nullptr);
            agg_lrelu<<<(Nn * 64 + 255) / 256, 256, 0, stream>>>(rowptr, csr, PS, br, yout, Nn);
            hipMemsetAsync(stats, 0, 512 * 4, stream);
            colstats<<<1024, 256, 0, stream>>>(yout, Nn, stats);
            bn_apply<<<(int)((nelem / 8 + 255) / 256), 256, 0, stream>>>(
                yout, stats, bg, bb, 1.0f / Nn, wl[l], tout, nelem);
            f16* tmp = yin; yin = yout; yout = tmp;
        }
    };

    run_tower(gene_x, g_ei, N_G, E_G, 5, gene_out);
    run_tower(disease_x, d_ei, N_D, E_D, 20, dis_out);

    const float* lin1_W = (const float*)d_in[35];
    const float* lin1_b = (const float*)d_in[36];
    const float* lin2_W = (const float*)d_in[37];
    const float* lin2_b = (const float*)d_in[38];
    const float* lin3_W = (const float*)d_in[39];
    const float* lin3_b = (const float*)d_in[40];
    const float* lin4_W = (const float*)d_in[41];
    const float* lin4_b = (const float*)d_in[42];

    transpose_tile<<<dim3(64, 16), dim3(32, 8), 0, stream>>>(lin1_W, W1T, 512, 2048, 0);
    transpose_tile<<<dim3(32, 64), dim3(32, 8), 0, stream>>>(lin2_W, W2T, 2048, 1024, 0);
    transpose_tile<<<dim3(16, 32), dim3(32, 8), 0, stream>>>(lin3_W, W3T, 1024, 512, 0);
    init_out<<<(BATCH * 2 + 255) / 256, 256, 0, stream>>>(lin4_b, out, BATCH * 2);

    for (int c = 0; c < chunks; c++) {
        int rb = c * R;
        int RB = R / 128;
        // lin1 with fused pair-gather from gene_out/dis_out
        gemm_f16<<<16 * RB, 256, 0, stream>>>(nullptr, bidx, gene_out, dis_out, rb,
                                              W1T, lin1_b, h1, R, 2048, 512, 1, 16, RB,
                                              nullptr, nullptr);
        gemm_f16<<<8 * RB, 256, 0, stream>>>(h1, nullptr, nullptr, nullptr, 0,
                                             W2T, lin2_b, h2, R, 1024, 2048, 1, 8, RB,
                                             nullptr, nullptr);
        // lin3 with fused lin4: atomics into out (fp32), rowBase=rb
        gemm_f16<<<4 * RB, 256, 0, stream>>>(h2, nullptr, nullptr, nullptr, rb,
                                             W3T, lin3_b, nullptr, R, 512, 1024, 1, 4, RB,
                                             lin4_W, out);
    }
}

// Round 2
// 1642.444 us; speedup vs baseline: 1.1851x; 1.0594x over previous
//
#include <hip/hip_runtime.h>
#include <hip/hip_bf16.h>
#include <cstdint>
#include <cstddef>

#define N_G 50000
#define N_D 20000
#define E_G 300000
#define E_D 150000
#define BATCH 65536

typedef _Float16 f16;
typedef _Float16 f16x8 __attribute__((ext_vector_type(8)));
typedef _Float16 f16x4 __attribute__((ext_vector_type(4)));
typedef float f32x4 __attribute__((ext_vector_type(4)));

__device__ __forceinline__ float clampf(float v) {
    return fminf(fmaxf(v, -60000.f), 60000.f);  // also squashes NaN
}

__device__ __forceinline__ void gl_lds16(const void* g, void* l) {
    __builtin_amdgcn_global_load_lds(
        (const __attribute__((address_space(1))) unsigned int*)g,
        (__attribute__((address_space(3))) unsigned int*)l, 16, 0, 0);
}

// ---------------- GEMM: C[M,N] = act(A[M,K] @ Bt[N,K]^T + bias) ----------------
// R7 structure (known-good): 128x128 tile, BK=64, 4 waves (2x2), 256 threads.
// - global_load_lds width-16 staging, XOR chunk swizzle (0 bank conflicts, R6)
// - XCD-aware block remap (requires RB%8==0)
// - A-operand modes:
//     plain:  A != null                     -> rows of A (K f16 each)
//     gather: bidx != null                  -> row r = [geneT[bidx[2r]] | disT[bidx[2r+1]]], K=512
//     concat: bidx == null, disT != null    -> row r = [geneT[r] | disT[r]], K=512 (tower pre-agg)
// - optional fused final linear (W4 != null): out[row] += lrelu(C_tile) @ W4 via atomics
// R8: vectorized epilogue — per-wave LDS transpose then f16x8 coalesced stores.
__global__ __launch_bounds__(256) void gemm_f16(
    const f16* __restrict__ A,
    const int* __restrict__ bidx,
    const f16* __restrict__ geneT, const f16* __restrict__ disT, int rowBase,
    const f16* __restrict__ Bt, const float* __restrict__ bias,
    f16* __restrict__ C, int M, int N, int K, int relu, int CB, int RB,
    const float* __restrict__ W4, float* __restrict__ outF)
{
    alignas(16) __shared__ f16 sA[128 * 64];
    alignas(16) __shared__ f16 sB[128 * 64];
    const int t = threadIdx.x;
    const int w = t >> 6, l = t & 63;
    const int wm = w >> 1, wn = w & 1;
    const int q = l >> 4, lr = l & 15;

    // XCD-aware remap (dispatch round-robins consecutive IDs across 8 XCDs)
    int flat = blockIdx.x;
    int cb, rb;
    if ((RB & 7) == 0) {
        int x = flat & 7, idx = flat >> 3;
        int Sx = RB >> 3;
        cb = idx % CB;
        rb = x * Sx + idx / CB;
    } else {
        cb = flat % CB;
        rb = flat / CB;
    }
    const int mBase = rb * 128, nBase = cb * 128;

    // staging: load j covers seg=j*4+w, LDS rows [seg*8, seg*8+8); lane -> (subrow, chunk)
    const int subrow = l >> 3;   // 0..7
    const int c = l & 7;         // 16B chunk 0..7 within a 128B row
    const char* pA[4];
    const char* pD[4];
    const char* pB[4];
    const bool fused = (bidx != nullptr);
    const bool concat = (!fused && disT != nullptr);
    const bool twoSrc = fused || concat;
#pragma unroll
    for (int j = 0; j < 4; j++) {
        int seg = j * 4 + w;
        int lrow = seg * 8 + subrow;               // 0..127
        int coff = ((c ^ (lrow & 7)) << 4);        // swizzled chunk byte offset
        if (fused) {
            int rg = rowBase + mBase + lrow;       // M % 128 == 0 on this path
            int gi = bidx[2 * rg], di = bidx[2 * rg + 1];
            pA[j] = (const char*)geneT + (size_t)gi * 512 + coff;
            pD[j] = (const char*)disT + (size_t)di * 512 + coff;
        } else if (concat) {
            int arow = mBase + lrow; if (arow > M - 1) arow = M - 1;
            pA[j] = (const char*)geneT + (size_t)arow * 512 + coff;
            pD[j] = (const char*)disT + (size_t)arow * 512 + coff;
        } else {
            int arow = mBase + lrow; if (arow > M - 1) arow = M - 1;
            pA[j] = (const char*)A + (size_t)arow * K * 2 + coff;
            pD[j] = nullptr;
        }
        int brow = nBase + lrow; if (brow > N - 1) brow = N - 1;
        pB[j] = (const char*)Bt + (size_t)brow * K * 2 + coff;
    }

    f32x4 acc[4][4] = {};

    for (int k0 = 0; k0 < K; k0 += 64) {
        __syncthreads();   // prev iter's LDS reads done
#pragma unroll
        for (int j = 0; j < 4; j++) {
            int seg = j * 4 + w;
            const char* srcA;
            if (twoSrc)
                srcA = (k0 < 256) ? (pA[j] + (size_t)k0 * 2) : (pD[j] + (size_t)(k0 - 256) * 2);
            else
                srcA = pA[j] + (size_t)k0 * 2;
            gl_lds16(srcA, sA + seg * 512);
            gl_lds16(pB[j] + (size_t)k0 * 2, sB + seg * 512);
        }
        __syncthreads();   // drain staging
        f16x8 a0[4], a1[4], b0[4], b1[4];
#pragma unroll
        for (int i = 0; i < 4; i++) {
            int r = wm * 64 + i * 16 + lr;
            int rs = r * 64;
            int x0 = (q ^ (r & 7)) << 3;
            int x1 = ((4 + q) ^ (r & 7)) << 3;
            a0[i] = *(const f16x8*)(sA + rs + x0);
            a1[i] = *(const f16x8*)(sA + rs + x1);
        }
#pragma unroll
        for (int jj = 0; jj < 4; jj++) {
            int r = wn * 64 + jj * 16 + lr;
            int rs = r * 64;
            int x0 = (q ^ (r & 7)) << 3;
            int x1 = ((4 + q) ^ (r & 7)) << 3;
            b0[jj] = *(const f16x8*)(sB + rs + x0);
            b1[jj] = *(const f16x8*)(sB + rs + x1);
        }
#pragma unroll
        for (int i = 0; i < 4; i++)
#pragma unroll
            for (int jj = 0; jj < 4; jj++) {
                acc[i][jj] = __builtin_amdgcn_mfma_f32_16x16x32_f16(a0[i], b0[jj], acc[i][jj], 0, 0, 0);
                acc[i][jj] = __builtin_amdgcn_mfma_f32_16x16x32_f16(a1[i], b1[jj], acc[i][jj], 0, 0, 0);
            }
    }

    if (W4 != nullptr) {
        // fused final linear: out[rowBase+row] += lrelu(acc + bias) @ W4 (512x2)
        float w40[4], w41[4];
#pragma unroll
        for (int j = 0; j < 4; j++) {
            int col = nBase + wn * 64 + j * 16 + lr;
            w40[j] = W4[col * 2];
            w41[j] = W4[col * 2 + 1];
        }
#pragma unroll
        for (int i = 0; i < 4; i++) {
#pragma unroll
            for (int r = 0; r < 4; r++) {
                int row = mBase + wm * 64 + i * 16 + q * 4 + r;
                float s0 = 0.f, s1 = 0.f;
#pragma unroll
                for (int j = 0; j < 4; j++) {
                    int col = nBase + wn * 64 + j * 16 + lr;
                    float v = acc[i][j][r] + bias[col];
                    v = v >= 0.f ? v : 0.01f * v;
                    v = clampf(v);
                    s0 += v * w40[j];
                    s1 += v * w41[j];
                }
#pragma unroll
                for (int off = 1; off < 16; off <<= 1) {
                    s0 += __shfl_xor(s0, off);
                    s1 += __shfl_xor(s1, off);
                }
                if (lr == 0 && row < M) {
                    atomicAdd(&outF[(size_t)(rowBase + row) * 2], s0);
                    atomicAdd(&outF[(size_t)(rowBase + row) * 2 + 1], s1);
                }
            }
        }
        return;
    }

    // ---- R8 epilogue: per-wave LDS transpose, then coalesced f16x8 stores ----
    __syncthreads();   // all waves done reading sA/sB from the K-loop
    f16* lt = ((w >> 1) ? sB : sA) + (w & 1) * 4096;

    float bj[4];
#pragma unroll
    for (int j = 0; j < 4; j++)
        bj[j] = bias ? bias[nBase + wn * 64 + j * 16 + lr] : 0.f;

#pragma unroll
    for (int i = 0; i < 4; i++)
#pragma unroll
        for (int j = 0; j < 4; j++) {
            int col = j * 16 + lr;
#pragma unroll
            for (int r = 0; r < 4; r++) {
                int row = i * 16 + q * 4 + r;       // 0..63 wave-local
                float v = acc[i][j][r] + bj[j];
                if (relu) v = v >= 0.f ? v : 0.01f * v;
                v = clampf(v);
                int cs = col ^ ((((row >> 2) & 3) << 4) ^ ((row & 3) << 3));
                lt[row * 64 + cs] = (f16)v;
            }
        }
    __syncthreads();

    const int rr = l >> 3;      // 0..7: row-within-group
    const int c8 = l & 7;       // 16B chunk within a 128B row
#pragma unroll
    for (int it = 0; it < 8; it++) {
        int row = it * 8 + rr;                      // 0..63 wave-local
        int cs = (c8 * 8) ^ ((((row >> 2) & 3) << 4) ^ ((row & 3) << 3));
        f16x8 vv = *(const f16x8*)(lt + row * 64 + cs);
        int grow = mBase + wm * 64 + row;
        if (grow < M)
            *(f16x8*)(C + (size_t)grow * N + nBase + wn * 64 + c8 * 8) = vv;
    }
}

// ---------------- small kernels ----------------
__global__ void cvt_f32_f16(const float* __restrict__ in, f16* __restrict__ out, size_t n) {
    size_t i = ((size_t)blockIdx.x * 256 + threadIdx.x) * 8;
    if (i >= n) return;
    f32x4 a = *(const f32x4*)(in + i);
    f32x4 b = *(const f32x4*)(in + i + 4);
    f16x8 o;
    o[0] = (f16)clampf(a.x); o[1] = (f16)clampf(a.y);
    o[2] = (f16)clampf(a.z); o[3] = (f16)clampf(a.w);
    o[4] = (f16)clampf(b.x); o[5] = (f16)clampf(b.y);
    o[6] = (f16)clampf(b.z); o[7] = (f16)clampf(b.w);
    *(f16x8*)(out + i) = o;
}

__global__ void init_out(const float* __restrict__ b4, float* __restrict__ out, int n) {
    int i = blockIdx.x * 256 + threadIdx.x;
    if (i < n) out[i] = b4[i & 1];
}

__global__ void count_deg(const int* __restrict__ ei, int E, int* __restrict__ deg) {
    int e = blockIdx.x * 256 + threadIdx.x;
    if (e < E) atomicAdd(&deg[ei[E + e]], 1);
}

__global__ void scan_deg(const int* __restrict__ deg, int* __restrict__ rowptr, int Nn) {
    __shared__ int part[1024];
    const int t = threadIdx.x;
    const int C = (Nn + 1023) >> 10;
    const int base = t * C;
    int s = 0;
    for (int i = 0; i < C; i++) { int idx = base + i; if (idx < Nn) s += deg[idx]; }
    part[t] = s;
    __syncthreads();
    for (int off = 1; off < 1024; off <<= 1) {
        int v = (t >= off) ? part[t - off] : 0;
        __syncthreads();
        part[t] += v;
        __syncthreads();
    }
    int pre = (t == 0) ? 0 : part[t - 1];
    for (int i = 0; i < C; i++) {
        int idx = base + i;
        if (idx < Nn) { rowptr[idx] = pre; pre += deg[idx]; }
    }
    if (t == 1023) rowptr[Nn] = part[1023];
}

__global__ void fill_csr(const int* __restrict__ ei, int E, const int* __restrict__ rowptr,
                         int* __restrict__ cursor, int* __restrict__ csr) {
    int e = blockIdx.x * 256 + threadIdx.x;
    if (e < E) {
        int d = ei[E + e];
        int p = rowptr[d] + atomicAdd(&cursor[d], 1);
        csr[p] = ei[e];
    }
}

// R9: pre-aggregation (GraphConv linearity): XA[i] = sum_{j->i} X[j].
// Gather reads the 25.6MB X buffer (L2/LLC-friendly) instead of the 51.2MB PS buffer.
// One wave per node; lane l owns cols l*4..l*4+3 (full 512B row per edge, coalesced).
__global__ void agg_x(const int* __restrict__ rowptr, const int* __restrict__ csr,
                      const f16* __restrict__ X, f16* __restrict__ XA, int Nn) {
    int gid = blockIdx.x * 256 + threadIdx.x;
    int node = gid >> 6, l = gid & 63;
    if (node >= Nn) return;
    int beg = rowptr[node], end = rowptr[node + 1];
    float s0 = 0.f, s1 = 0.f, s2 = 0.f, s3 = 0.f;
    for (int e = beg; e < end; e++) {
        int src = csr[e];
        f16x4 xv = *(const f16x4*)(X + (size_t)src * 256 + l * 4);
        s0 += (float)xv.x; s1 += (float)xv.y; s2 += (float)xv.z; s3 += (float)xv.w;
    }
    f16x4 o;
    o.x = (f16)clampf(s0); o.y = (f16)clampf(s1);
    o.z = (f16)clampf(s2); o.w = (f16)clampf(s3);
    *(f16x4*)(XA + (size_t)node * 256 + l * 4) = o;
}

// Tiled transpose: WT[(dstRowOff+n)*LK + dstColOff + k] = W[k][n]; W is K x N fp32.
// Coalesced on both sides via 32x33 LDS tile. block (32,8), grid (ceil(N/32), ceil(K/32)).
__global__ void transpose_tile(const float* __restrict__ W, f16* __restrict__ WT,
                               int K, int N, int dstRowOff, int dstColOff, int LK) {
    __shared__ float tile[32][33];
    int n0 = blockIdx.x * 32, k0 = blockIdx.y * 32;
    int tx = threadIdx.x, ty = threadIdx.y;
    for (int yy = ty; yy < 32; yy += 8) {
        int k = k0 + yy, n = n0 + tx;
        tile[yy][tx] = (k < K && n < N) ? W[(size_t)k * N + n] : 0.f;
    }
    __syncthreads();
    for (int yy = ty; yy < 32; yy += 8) {
        int n = n0 + yy, k = k0 + tx;
        if (n < N && k < K)
            WT[(size_t)(dstRowOff + n) * LK + dstColOff + k] = (f16)clampf(tile[tx][yy]);
    }
}

__global__ void colstats(const f16* __restrict__ y, int Nrows, float* __restrict__ stats) {
    int col = threadIdx.x;  // 256
    float s = 0, s2 = 0;
    for (int r = blockIdx.x; r < Nrows; r += gridDim.x) {
        float v = (float)y[(size_t)r * 256 + col];
        s += v; s2 += v * v;
    }
    atomicAdd(&stats[col], s);
    atomicAdd(&stats[256 + col], s2);
}

// BN on y; acc (f16, persistent) = (initAcc ? 0 : acc) + w * BN(y).  Vectorized x8.
__global__ void bn_apply(f16* __restrict__ y, const float* __restrict__ stats,
                         const float* __restrict__ g, const float* __restrict__ b,
                         float invN, float w, f16* __restrict__ acc, size_t total,
                         int initAcc) {
    size_t i = ((size_t)blockIdx.x * 256 + threadIdx.x) * 8;
    if (i >= total) return;
    int colb = (int)(i & 255);
    f16x8 yv = *(const f16x8*)(y + i);
    f16x8 av = {};
    if (!initAcc) av = *(const f16x8*)(acc + i);
    f16x8 yo, ao;
#pragma unroll
    for (int j = 0; j < 8; j++) {
        int col = colb + j;
        float m = stats[col] * invN;
        float var = stats[256 + col] * invN - m * m;
        if (var < 0.f) var = 0.f;
        float rs = 1.0f / sqrtf(var + 1e-5f);
        float v = ((float)yv[j] - m) * rs * g[col] + b[col];
        v = clampf(v);
        yo[j] = (f16)v;
        float p = initAcc ? 0.f : (float)av[j];
        ao[j] = (f16)clampf(p + w * v);
    }
    *(f16x8*)(y + i) = yo;
    *(f16x8*)(acc + i) = ao;
}

extern "C" void kernel_launch(void* const* d_in, const int* in_sizes, int n_in,
                              void* d_out, int out_size, void* d_ws, size_t ws_size,
                              hipStream_t stream) {
    char* ws = (char*)d_ws;
    size_t off = 0;
    auto alloc = [&](size_t bytes) -> void* {
        void* p = ws + off;
        off += (bytes + 255) & ~(size_t)255;
        return p;
    };

    // persistent (~45 MB)
    f16* gene_out = (f16*)alloc((size_t)N_G * 256 * 2);
    f16* dis_out  = (f16*)alloc((size_t)N_D * 256 * 2);
    f16* W1T = (f16*)alloc((size_t)2048 * 512 * 2);
    f16* W2T = (f16*)alloc((size_t)1024 * 2048 * 2);
    f16* W3T = (f16*)alloc((size_t)512 * 1024 * 2);
    f16* WcatT = (f16*)alloc((size_t)256 * 512 * 2);   // 256 out-cols x (Ws|Wr) 512-K
    int* csr = (int*)alloc((size_t)E_G * 4);
    int* rowptr = (int*)alloc((size_t)(N_G + 1) * 4);
    int* cnt = (int*)alloc((size_t)N_G * 4);
    float* stats = (float*)alloc(512 * 4);

    // scratch: towers use ybA + ybB + XAbuf (25.6 MB each); head aliases it
    char* scratch = ws + off;
    size_t avail = (ws_size > off) ? (ws_size - off) : 0;

    f16* ybA = (f16*)scratch;
    f16* ybB = ybA + (size_t)N_G * 256;
    f16* XAbuf = ybB + (size_t)N_G * 256;

    // head chunk: R rows use R*6144 bytes (h1 4KB + h2 2KB per row; h3 fused away)
    // R9: R=32768 so h1(134MB)+h2(67MB)+gather src(36MB) fits the 256MB LLC
    int R = 32768;
    while ((size_t)R * 6144 > avail && R > 256) R >>= 1;
    int chunks = BATCH / R;
    f16* h1 = (f16*)scratch;
    f16* h2 = h1 + (size_t)R * 2048;

    const float* gene_x = (const float*)d_in[0];
    const float* disease_x = (const float*)d_in[1];
    const int* g_ei = (const int*)d_in[2];
    const int* d_ei = (const int*)d_in[3];
    const int* bidx = (const int*)d_in[4];
    float* out = (float*)d_out;

    const float wl[3] = {0.7f, 0.2f, 0.1f};

    auto run_tower = [&](const float* xin, const int* ei, int Nn, int E, int pbase, f16* tout) {
        size_t nelem = (size_t)Nn * 256;
        cvt_f32_f16<<<(int)((nelem / 8 + 255) / 256), 256, 0, stream>>>(xin, ybA, nelem);
        hipMemsetAsync(cnt, 0, (size_t)Nn * 4, stream);
        count_deg<<<(E + 255) / 256, 256, 0, stream>>>(ei, E, cnt);
        scan_deg<<<1, 1024, 0, stream>>>(cnt, rowptr, Nn);
        hipMemsetAsync(cnt, 0, (size_t)Nn * 4, stream);
        fill_csr<<<(E + 255) / 256, 256, 0, stream>>>(ei, E, rowptr, cnt, csr);
        f16* yin = ybA;
        f16* yout = ybB;
        int RB = (Nn + 127) / 128;
        int RBp = (RB + 7) & ~7;   // pad so the in-kernel XCD remap engages
        for (int l = 0; l < 3; l++) {
            const float* Wr = (const float*)d_in[pbase + l * 5 + 0];
            const float* br = (const float*)d_in[pbase + l * 5 + 1];
            const float* Wss = (const float*)d_in[pbase + l * 5 + 2];
            const float* bg = (const float*)d_in[pbase + l * 5 + 3];
            const float* bb = (const float*)d_in[pbase + l * 5 + 4];
            // B rows: [Ws-cols (k<256) | Wr-cols (k>=256)] matching A = [X | XA]
            transpose_tile<<<dim3(8, 8), dim3(32, 8), 0, stream>>>(Wss, WcatT, 256, 256, 0, 0, 512);
            transpose_tile<<<dim3(8, 8), dim3(32, 8), 0, stream>>>(Wr, WcatT, 256, 256, 0, 256, 512);
            // XA = gather-sum of yin rows
            agg_x<<<(Nn * 64 + 255) / 256, 256, 0, stream>>>(rowptr, csr, yin, XAbuf, Nn);
            // y = lrelu([X|XA] @ [Ws;Wr] + br)   (M=Nn, N=256, K=512, concat mode)
            gemm_f16<<<2 * RBp, 256, 0, stream>>>(nullptr, nullptr, yin, XAbuf, 0,
                                                  WcatT, br, yout, Nn, 256, 512, 1, 2, RBp,
                                                  nullptr, nullptr);
            hipMemsetAsync(stats, 0, 512 * 4, stream);
            colstats<<<1024, 256, 0, stream>>>(yout, Nn, stats);
            bn_apply<<<(int)((nelem / 8 + 255) / 256), 256, 0, stream>>>(
                yout, stats, bg, bb, 1.0f / Nn, wl[l], tout, nelem, l == 0);
            f16* tmp = yin; yin = yout; yout = tmp;
        }
    };

    run_tower(gene_x, g_ei, N_G, E_G, 5, gene_out);
    run_tower(disease_x, d_ei, N_D, E_D, 20, dis_out);

    const float* lin1_W = (const float*)d_in[35];
    const float* lin1_b = (const float*)d_in[36];
    const float* lin2_W = (const float*)d_in[37];
    const float* lin2_b = (const float*)d_in[38];
    const float* lin3_W = (const float*)d_in[39];
    const float* lin3_b = (const float*)d_in[40];
    const float* lin4_W = (const float*)d_in[41];
    const float* lin4_b = (const float*)d_in[42];

    transpose_tile<<<dim3(64, 16), dim3(32, 8), 0, stream>>>(lin1_W, W1T, 512, 2048, 0, 0, 512);
    transpose_tile<<<dim3(32, 64), dim3(32, 8), 0, stream>>>(lin2_W, W2T, 2048, 1024, 0, 0, 2048);
    transpose_tile<<<dim3(16, 32), dim3(32, 8), 0, stream>>>(lin3_W, W3T, 1024, 512, 0, 0, 1024);
    init_out<<<(BATCH * 2 + 255) / 256, 256, 0, stream>>>(lin4_b, out, BATCH * 2);

    for (int c = 0; c < chunks; c++) {
        int rb = c * R;
        int RB = R / 128;
        // lin1 with fused pair-gather from gene_out/dis_out
        gemm_f16<<<16 * RB, 256, 0, stream>>>(nullptr, bidx, gene_out, dis_out, rb,
                                              W1T, lin1_b, h1, R, 2048, 512, 1, 16, RB,
                                              nullptr, nullptr);
        gemm_f16<<<8 * RB, 256, 0, stream>>>(h1, nullptr, nullptr, nullptr, 0,
                                             W2T, lin2_b, h2, R, 1024, 2048, 1, 8, RB,
                                             nullptr, nullptr);
        // lin3 with fused lin4: atomics into out (fp32), rowBase=rb
        gemm_f16<<<4 * RB, 256, 0, stream>>>(h2, nullptr, nullptr, nullptr, rb,
                                             W3T, lin3_b, nullptr, R, 512, 1024, 1, 4, RB,
                                             lin4_W, out);
    }
}

// Round 3
// 1484.404 us; speedup vs baseline: 1.3113x; 1.1065x over previous
//
#include <hip/hip_runtime.h>
#include <hip/hip_bf16.h>
#include <cstdint>
#include <cstddef>

#define N_G 50000
#define N_D 20000
#define E_G 300000
#define E_D 150000
#define BATCH 65536

typedef _Float16 f16;
typedef _Float16 f16x8 __attribute__((ext_vector_type(8)));
typedef _Float16 f16x4 __attribute__((ext_vector_type(4)));
typedef float f32x4 __attribute__((ext_vector_type(4)));

__device__ __forceinline__ float clampf(float v) {
    return fminf(fmaxf(v, -60000.f), 60000.f);  // also squashes NaN
}

__device__ __forceinline__ void gl_lds16(const void* g, void* l) {
    __builtin_amdgcn_global_load_lds(
        (const __attribute__((address_space(1))) unsigned int*)g,
        (__attribute__((address_space(3))) unsigned int*)l, 16, 0, 0);
}

// ---------------- GEMM (128x128, 4 waves): C = act(A @ Bt^T + bias) ----------------
// Proven R7/R8 structure. Used for tower layers (N=256) and lin3(+fused lin4).
// R10: optional fused column-stats (sum, sumsq) for BN -> stats[0..255]/[256..511].
__global__ __launch_bounds__(256) void gemm_f16(
    const f16* __restrict__ A,
    const int* __restrict__ bidx,
    const f16* __restrict__ geneT, const f16* __restrict__ disT, int rowBase,
    const f16* __restrict__ Bt, const float* __restrict__ bias,
    f16* __restrict__ C, int M, int N, int K, int relu, int CB, int RB,
    const float* __restrict__ W4, float* __restrict__ outF,
    float* __restrict__ stats)
{
    alignas(16) __shared__ f16 sA[128 * 64];
    alignas(16) __shared__ f16 sB[128 * 64];
    const int t = threadIdx.x;
    const int w = t >> 6, l = t & 63;
    const int wm = w >> 1, wn = w & 1;
    const int q = l >> 4, lr = l & 15;

    int flat = blockIdx.x;
    int cb, rb;
    if ((RB & 7) == 0) {
        int x = flat & 7, idx = flat >> 3;
        int Sx = RB >> 3;
        cb = idx % CB;
        rb = x * Sx + idx / CB;
    } else {
        cb = flat % CB;
        rb = flat / CB;
    }
    const int mBase = rb * 128, nBase = cb * 128;

    const int subrow = l >> 3;   // 0..7
    const int c = l & 7;         // 16B chunk 0..7 within a 128B row
    const char* pA[4];
    const char* pD[4];
    const char* pB[4];
    const bool fused = (bidx != nullptr);
    const bool concat = (!fused && disT != nullptr);
    const bool twoSrc = fused || concat;
#pragma unroll
    for (int j = 0; j < 4; j++) {
        int seg = j * 4 + w;
        int lrow = seg * 8 + subrow;               // 0..127
        int coff = ((c ^ (lrow & 7)) << 4);        // swizzled chunk byte offset
        if (fused) {
            int rg = rowBase + mBase + lrow;       // M % 128 == 0 on this path
            int gi = bidx[2 * rg], di = bidx[2 * rg + 1];
            pA[j] = (const char*)geneT + (size_t)gi * 512 + coff;
            pD[j] = (const char*)disT + (size_t)di * 512 + coff;
        } else if (concat) {
            int arow = mBase + lrow; if (arow > M - 1) arow = M - 1;
            pA[j] = (const char*)geneT + (size_t)arow * 512 + coff;
            pD[j] = (const char*)disT + (size_t)arow * 512 + coff;
        } else {
            int arow = mBase + lrow; if (arow > M - 1) arow = M - 1;
            pA[j] = (const char*)A + (size_t)arow * K * 2 + coff;
            pD[j] = nullptr;
        }
        int brow = nBase + lrow; if (brow > N - 1) brow = N - 1;
        pB[j] = (const char*)Bt + (size_t)brow * K * 2 + coff;
    }

    f32x4 acc[4][4] = {};

    for (int k0 = 0; k0 < K; k0 += 64) {
        __syncthreads();
#pragma unroll
        for (int j = 0; j < 4; j++) {
            int seg = j * 4 + w;
            const char* srcA;
            if (twoSrc)
                srcA = (k0 < 256) ? (pA[j] + (size_t)k0 * 2) : (pD[j] + (size_t)(k0 - 256) * 2);
            else
                srcA = pA[j] + (size_t)k0 * 2;
            gl_lds16(srcA, sA + seg * 512);
            gl_lds16(pB[j] + (size_t)k0 * 2, sB + seg * 512);
        }
        __syncthreads();
        f16x8 a0[4], a1[4], b0[4], b1[4];
#pragma unroll
        for (int i = 0; i < 4; i++) {
            int r = wm * 64 + i * 16 + lr;
            int rs = r * 64;
            int x0 = (q ^ (r & 7)) << 3;
            int x1 = ((4 + q) ^ (r & 7)) << 3;
            a0[i] = *(const f16x8*)(sA + rs + x0);
            a1[i] = *(const f16x8*)(sA + rs + x1);
        }
#pragma unroll
        for (int jj = 0; jj < 4; jj++) {
            int r = wn * 64 + jj * 16 + lr;
            int rs = r * 64;
            int x0 = (q ^ (r & 7)) << 3;
            int x1 = ((4 + q) ^ (r & 7)) << 3;
            b0[jj] = *(const f16x8*)(sB + rs + x0);
            b1[jj] = *(const f16x8*)(sB + rs + x1);
        }
#pragma unroll
        for (int i = 0; i < 4; i++)
#pragma unroll
            for (int jj = 0; jj < 4; jj++) {
                acc[i][jj] = __builtin_amdgcn_mfma_f32_16x16x32_f16(a0[i], b0[jj], acc[i][jj], 0, 0, 0);
                acc[i][jj] = __builtin_amdgcn_mfma_f32_16x16x32_f16(a1[i], b1[jj], acc[i][jj], 0, 0, 0);
            }
    }

    if (W4 != nullptr) {
        // fused final linear: out[rowBase+row] += lrelu(acc + bias) @ W4 (512x2)
        float w40[4], w41[4];
#pragma unroll
        for (int j = 0; j < 4; j++) {
            int col = nBase + wn * 64 + j * 16 + lr;
            w40[j] = W4[col * 2];
            w41[j] = W4[col * 2 + 1];
        }
#pragma unroll
        for (int i = 0; i < 4; i++) {
#pragma unroll
            for (int r = 0; r < 4; r++) {
                int row = mBase + wm * 64 + i * 16 + q * 4 + r;
                float s0 = 0.f, s1 = 0.f;
#pragma unroll
                for (int j = 0; j < 4; j++) {
                    int col = nBase + wn * 64 + j * 16 + lr;
                    float v = acc[i][j][r] + bias[col];
                    v = v >= 0.f ? v : 0.01f * v;
                    v = clampf(v);
                    s0 += v * w40[j];
                    s1 += v * w41[j];
                }
#pragma unroll
                for (int off = 1; off < 16; off <<= 1) {
                    s0 += __shfl_xor(s0, off);
                    s1 += __shfl_xor(s1, off);
                }
                if (lr == 0 && row < M) {
                    atomicAdd(&outF[(size_t)(rowBase + row) * 2], s0);
                    atomicAdd(&outF[(size_t)(rowBase + row) * 2 + 1], s1);
                }
            }
        }
        return;
    }

    // ---- epilogue: per-wave LDS transpose, then coalesced f16x8 stores ----
    __syncthreads();
    f16* lt = ((w >> 1) ? sB : sA) + (w & 1) * 4096;

    float bj[4];
#pragma unroll
    for (int j = 0; j < 4; j++)
        bj[j] = bias ? bias[nBase + wn * 64 + j * 16 + lr] : 0.f;

    float sj[4] = {0.f, 0.f, 0.f, 0.f}, s2j[4] = {0.f, 0.f, 0.f, 0.f};
#pragma unroll
    for (int i = 0; i < 4; i++)
#pragma unroll
        for (int j = 0; j < 4; j++) {
            int col = j * 16 + lr;
#pragma unroll
            for (int r = 0; r < 4; r++) {
                int row = i * 16 + q * 4 + r;       // 0..63 wave-local
                float v = acc[i][j][r] + bj[j];
                if (relu) v = v >= 0.f ? v : 0.01f * v;
                v = clampf(v);
                if (stats && (mBase + wm * 64 + row) < M) { sj[j] += v; s2j[j] += v * v; }
                int cs = col ^ ((((row >> 2) & 3) << 4) ^ ((row & 3) << 3));
                lt[row * 64 + cs] = (f16)v;
            }
        }

    if (stats) {
        // reduce over q (lanes ^16, ^32 share lr), one atomic pair per column per wave
#pragma unroll
        for (int j = 0; j < 4; j++) {
            float s = sj[j], s2 = s2j[j];
            s += __shfl_xor(s, 16); s2 += __shfl_xor(s2, 16);
            s += __shfl_xor(s, 32); s2 += __shfl_xor(s2, 32);
            if (q == 0) {
                int col = nBase + wn * 64 + j * 16 + lr;
                if (col < 256 && col < N) {
                    atomicAdd(&stats[col], s);
                    atomicAdd(&stats[256 + col], s2);
                }
            }
        }
    }
    __syncthreads();

    const int rr = l >> 3;
    const int c8 = l & 7;
#pragma unroll
    for (int it = 0; it < 8; it++) {
        int row = it * 8 + rr;
        int cs = (c8 * 8) ^ ((((row >> 2) & 3) << 4) ^ ((row & 3) << 3));
        f16x8 vv = *(const f16x8*)(lt + row * 64 + cs);
        int grow = mBase + wm * 64 + row;
        if (grow < M)
            *(f16x8*)(C + (size_t)grow * N + nBase + wn * 64 + c8 * 8) = vv;
    }
}

// ---------------- GEMM 256x256, 8 waves, double-buffered, counted-vmcnt ----------------
// R10: head GEMMs (lin1 gather / lin2 plain). BK=64; LDS = 2 x (A 32KB + B 32KB) = 128KB.
// Per wave: output 128x64 (acc 8x4), reads only A-half wm / B-quarter wn.
// K-loop: STAGE(next buf) -> s_waitcnt vmcnt(8) (counted, never 0 mid-loop) ->
// raw s_barrier -> ds_read+MFMA -> s_barrier. __syncthreads is NOT used in the loop
// (hipcc emits vmcnt(0) before it, which would drain the prefetch).
__global__ __launch_bounds__(512) void gemm256(
    const f16* __restrict__ A,
    const int* __restrict__ bidx,
    const f16* __restrict__ geneT, const f16* __restrict__ disT, int rowBase,
    const f16* __restrict__ Bt, const float* __restrict__ bias,
    f16* __restrict__ C, int M, int N, int K, int relu, int CB, int RB)
{
    alignas(16) __shared__ f16 sm[65536];   // [buf0: A 16384 | B 16384][buf1: ...]
    const int t = threadIdx.x;
    const int w = t >> 6, l = t & 63;
    const int wm = w >> 2, wn = w & 3;      // 2 x 4 wave grid
    const int q = l >> 4, lr = l & 15;

    int flat = blockIdx.x;
    int cb, rb;
    if ((RB & 7) == 0) {
        int x = flat & 7, idx = flat >> 3;
        int Sx = RB >> 3;
        cb = idx % CB;
        rb = x * Sx + idx / CB;
    } else {
        cb = flat % CB;
        rb = flat / CB;
    }
    const int mBase = rb * 256, nBase = cb * 256;

    const int subrow = l >> 3;   // 0..7
    const int c = l & 7;         // 16B chunk within a 128B row
    const bool gat = (bidx != nullptr);
    const char* pA[4];
    const char* pD[4];
    const char* pB[4];
#pragma unroll
    for (int jj = 0; jj < 4; jj++) {
        int arow = jj * 64 + w * 8 + subrow;        // 0..255 tile-local row
        int coff = ((c ^ (arow & 7)) << 4);         // inverse-swizzled source chunk
        if (gat) {
            int rg = rowBase + mBase + arow;        // M % 256 == 0 on this path
            int gi = bidx[2 * rg], di = bidx[2 * rg + 1];
            pA[jj] = (const char*)geneT + (size_t)gi * 512 + coff;
            pD[jj] = (const char*)disT + (size_t)di * 512 + coff;
        } else {
            int ga = mBase + arow; if (ga > M - 1) ga = M - 1;
            pA[jj] = (const char*)A + (size_t)ga * K * 2 + coff;
            pD[jj] = nullptr;
        }
        int gb = nBase + arow; if (gb > N - 1) gb = N - 1;
        pB[jj] = (const char*)Bt + (size_t)gb * K * 2 + coff;
    }

    // stage one K-step (A 256x64 + B 256x64) into buffer cbuf: 8 gl_lds / thread
    auto stage = [&](int cbuf, int k0) {
        f16* bA = sm + cbuf * 32768;
        f16* bB = bA + 16384;
#pragma unroll
        for (int jj = 0; jj < 4; jj++) {
            int R0 = jj * 64 + w * 8;               // wave-uniform LDS row base
            const char* srcA;
            if (gat)
                srcA = (k0 < 256) ? (pA[jj] + (size_t)k0 * 2) : (pD[jj] + (size_t)(k0 - 256) * 2);
            else
                srcA = pA[jj] + (size_t)k0 * 2;
            gl_lds16(srcA, bA + R0 * 64);
            gl_lds16(pB[jj] + (size_t)k0 * 2, bB + R0 * 64);
        }
    };

    f32x4 acc[8][4] = {};
    const int nkt = K >> 6;

    stage(0, 0);
    int cur = 0;
    for (int kt = 0; kt < nkt; kt++) {
        if (kt + 1 < nkt) {
            stage(cur ^ 1, (kt + 1) << 6);
            asm volatile("s_waitcnt vmcnt(8)" ::: "memory");  // wait buf[cur] only
        } else {
            asm volatile("s_waitcnt vmcnt(0)" ::: "memory");
        }
        __builtin_amdgcn_s_barrier();
        __builtin_amdgcn_sched_barrier(0);
        const f16* bA = sm + cur * 32768;
        const f16* bB = bA + 16384;
#pragma unroll
        for (int ks = 0; ks < 2; ks++) {
            f16x8 bf[4];
#pragma unroll
            for (int nf = 0; nf < 4; nf++) {
                int rB = wn * 64 + nf * 16 + lr;
                bf[nf] = *(const f16x8*)(bB + rB * 64 + ((((ks << 2) + q) ^ (rB & 7)) << 3));
            }
#pragma unroll
            for (int mf = 0; mf < 8; mf++) {
                int rA = wm * 128 + mf * 16 + lr;
                f16x8 af = *(const f16x8*)(bA + rA * 64 + ((((ks << 2) + q) ^ (rA & 7)) << 3));
#pragma unroll
                for (int nf = 0; nf < 4; nf++)
                    acc[mf][nf] = __builtin_amdgcn_mfma_f32_16x16x32_f16(af, bf[nf], acc[mf][nf], 0, 0, 0);
            }
        }
        __builtin_amdgcn_sched_barrier(0);
        __builtin_amdgcn_s_barrier();
        cur ^= 1;
    }
    __builtin_amdgcn_sched_barrier(0);

    // ---- epilogue: per-wave 128x64 LDS transpose (16KB slice), f16x8 stores ----
    f16* lt = sm + w * 8192;
    float bj[4];
#pragma unroll
    for (int nf = 0; nf < 4; nf++)
        bj[nf] = bias ? bias[nBase + wn * 64 + nf * 16 + lr] : 0.f;

#pragma unroll
    for (int mf = 0; mf < 8; mf++)
#pragma unroll
        for (int nf = 0; nf < 4; nf++) {
            int col = nf * 16 + lr;
#pragma unroll
            for (int r = 0; r < 4; r++) {
                int row = mf * 16 + q * 4 + r;      // 0..127 wave-local
                float v = acc[mf][nf][r] + bj[nf];
                if (relu) v = v >= 0.f ? v : 0.01f * v;
                v = clampf(v);
                int cs = col ^ ((((row >> 2) & 3) << 4) ^ ((row & 3) << 3));
                lt[row * 64 + cs] = (f16)v;
            }
        }

    const int rr = l >> 3;
    const int c8 = l & 7;
#pragma unroll
    for (int it = 0; it < 16; it++) {
        int row = it * 8 + rr;                      // 0..127 wave-local
        int cs = (c8 * 8) ^ ((((row >> 2) & 3) << 4) ^ ((row & 3) << 3));
        f16x8 vv = *(const f16x8*)(lt + row * 64 + cs);
        int grow = mBase + wm * 128 + row;
        if (grow < M)
            *(f16x8*)(C + (size_t)grow * N + nBase + wn * 64 + c8 * 8) = vv;
    }
}

// ---------------- small kernels ----------------
__global__ void cvt_f32_f16(const float* __restrict__ in, f16* __restrict__ out, size_t n) {
    size_t i = ((size_t)blockIdx.x * 256 + threadIdx.x) * 8;
    if (i >= n) return;
    f32x4 a = *(const f32x4*)(in + i);
    f32x4 b = *(const f32x4*)(in + i + 4);
    f16x8 o;
    o[0] = (f16)clampf(a.x); o[1] = (f16)clampf(a.y);
    o[2] = (f16)clampf(a.z); o[3] = (f16)clampf(a.w);
    o[4] = (f16)clampf(b.x); o[5] = (f16)clampf(b.y);
    o[6] = (f16)clampf(b.z); o[7] = (f16)clampf(b.w);
    *(f16x8*)(out + i) = o;
}

__global__ void init_out(const float* __restrict__ b4, float* __restrict__ out, int n) {
    int i = blockIdx.x * 256 + threadIdx.x;
    if (i < n) out[i] = b4[i & 1];
}

__global__ void count_deg(const int* __restrict__ ei, int E, int* __restrict__ deg) {
    int e = blockIdx.x * 256 + threadIdx.x;
    if (e < E) atomicAdd(&deg[ei[E + e]], 1);
}

__global__ void scan_deg(const int* __restrict__ deg, int* __restrict__ rowptr, int Nn) {
    __shared__ int part[1024];
    const int t = threadIdx.x;
    const int C = (Nn + 1023) >> 10;
    const int base = t * C;
    int s = 0;
    for (int i = 0; i < C; i++) { int idx = base + i; if (idx < Nn) s += deg[idx]; }
    part[t] = s;
    __syncthreads();
    for (int off = 1; off < 1024; off <<= 1) {
        int v = (t >= off) ? part[t - off] : 0;
        __syncthreads();
        part[t] += v;
        __syncthreads();
    }
    int pre = (t == 0) ? 0 : part[t - 1];
    for (int i = 0; i < C; i++) {
        int idx = base + i;
        if (idx < Nn) { rowptr[idx] = pre; pre += deg[idx]; }
    }
    if (t == 1023) rowptr[Nn] = part[1023];
}

__global__ void fill_csr(const int* __restrict__ ei, int E, const int* __restrict__ rowptr,
                         int* __restrict__ cursor, int* __restrict__ csr) {
    int e = blockIdx.x * 256 + threadIdx.x;
    if (e < E) {
        int d = ei[E + e];
        int p = rowptr[d] + atomicAdd(&cursor[d], 1);
        csr[p] = ei[e];
    }
}

// pre-aggregation (GraphConv linearity): XA[i] = sum_{j->i} X[j]
__global__ void agg_x(const int* __restrict__ rowptr, const int* __restrict__ csr,
                      const f16* __restrict__ X, f16* __restrict__ XA, int Nn) {
    int gid = blockIdx.x * 256 + threadIdx.x;
    int node = gid >> 6, l = gid & 63;
    if (node >= Nn) return;
    int beg = rowptr[node], end = rowptr[node + 1];
    float s0 = 0.f, s1 = 0.f, s2 = 0.f, s3 = 0.f;
    for (int e = beg; e < end; e++) {
        int src = csr[e];
        f16x4 xv = *(const f16x4*)(X + (size_t)src * 256 + l * 4);
        s0 += (float)xv.x; s1 += (float)xv.y; s2 += (float)xv.z; s3 += (float)xv.w;
    }
    f16x4 o;
    o.x = (f16)clampf(s0); o.y = (f16)clampf(s1);
    o.z = (f16)clampf(s2); o.w = (f16)clampf(s3);
    *(f16x4*)(XA + (size_t)node * 256 + l * 4) = o;
}

// Tiled transpose: WT[(dstRowOff+n)*LK + dstColOff + k] = W[k][n]
__global__ void transpose_tile(const float* __restrict__ W, f16* __restrict__ WT,
                               int K, int N, int dstRowOff, int dstColOff, int LK) {
    __shared__ float tile[32][33];
    int n0 = blockIdx.x * 32, k0 = blockIdx.y * 32;
    int tx = threadIdx.x, ty = threadIdx.y;
    for (int yy = ty; yy < 32; yy += 8) {
        int k = k0 + yy, n = n0 + tx;
        tile[yy][tx] = (k < K && n < N) ? W[(size_t)k * N + n] : 0.f;
    }
    __syncthreads();
    for (int yy = ty; yy < 32; yy += 8) {
        int n = n0 + yy, k = k0 + tx;
        if (n < N && k < K)
            WT[(size_t)(dstRowOff + n) * LK + dstColOff + k] = (f16)clampf(tile[tx][yy]);
    }
}

// BN on y; acc (f16, persistent) = (initAcc ? 0 : acc) + w * BN(y).  Vectorized x8.
__global__ void bn_apply(f16* __restrict__ y, const float* __restrict__ stats,
                         const float* __restrict__ g, const float* __restrict__ b,
                         float invN, float w, f16* __restrict__ acc, size_t total,
                         int initAcc) {
    size_t i = ((size_t)blockIdx.x * 256 + threadIdx.x) * 8;
    if (i >= total) return;
    int colb = (int)(i & 255);
    f16x8 yv = *(const f16x8*)(y + i);
    f16x8 av = {};
    if (!initAcc) av = *(const f16x8*)(acc + i);
    f16x8 yo, ao;
#pragma unroll
    for (int j = 0; j < 8; j++) {
        int col = colb + j;
        float m = stats[col] * invN;
        float var = stats[256 + col] * invN - m * m;
        if (var < 0.f) var = 0.f;
        float rs = 1.0f / sqrtf(var + 1e-5f);
        float v = ((float)yv[j] - m) * rs * g[col] + b[col];
        v = clampf(v);
        yo[j] = (f16)v;
        float p = initAcc ? 0.f : (float)av[j];
        ao[j] = (f16)clampf(p + w * v);
    }
    *(f16x8*)(y + i) = yo;
    *(f16x8*)(acc + i) = ao;
}

extern "C" void kernel_launch(void* const* d_in, const int* in_sizes, int n_in,
                              void* d_out, int out_size, void* d_ws, size_t ws_size,
                              hipStream_t stream) {
    char* ws = (char*)d_ws;
    size_t off = 0;
    auto alloc = [&](size_t bytes) -> void* {
        void* p = ws + off;
        off += (bytes + 255) & ~(size_t)255;
        return p;
    };

    // persistent (~45 MB)
    f16* gene_out = (f16*)alloc((size_t)N_G * 256 * 2);
    f16* dis_out  = (f16*)alloc((size_t)N_D * 256 * 2);
    f16* W1T = (f16*)alloc((size_t)2048 * 512 * 2);
    f16* W2T = (f16*)alloc((size_t)1024 * 2048 * 2);
    f16* W3T = (f16*)alloc((size_t)512 * 1024 * 2);
    f16* WcatT = (f16*)alloc((size_t)256 * 512 * 2);
    int* csr = (int*)alloc((size_t)E_G * 4);
    int* rowptr = (int*)alloc((size_t)(N_G + 1) * 4);
    int* cnt = (int*)alloc((size_t)N_G * 4);
    float* stats = (float*)alloc(512 * 4);

    char* scratch = ws + off;
    size_t avail = (ws_size > off) ? (ws_size - off) : 0;

    f16* ybA = (f16*)scratch;
    f16* ybB = ybA + (size_t)N_G * 256;
    f16* XAbuf = ybB + (size_t)N_G * 256;

    // head chunk: R rows use R*6144 bytes (h1 4KB + h2 2KB per row)
    int R = 32768;
    while ((size_t)R * 6144 > avail && R > 256) R >>= 1;
    int chunks = BATCH / R;
    f16* h1 = (f16*)scratch;
    f16* h2 = h1 + (size_t)R * 2048;

    const float* gene_x = (const float*)d_in[0];
    const float* disease_x = (const float*)d_in[1];
    const int* g_ei = (const int*)d_in[2];
    const int* d_ei = (const int*)d_in[3];
    const int* bidx = (const int*)d_in[4];
    float* out = (float*)d_out;

    const float wl[3] = {0.7f, 0.2f, 0.1f};

    auto run_tower = [&](const float* xin, const int* ei, int Nn, int E, int pbase, f16* tout) {
        size_t nelem = (size_t)Nn * 256;
        cvt_f32_f16<<<(int)((nelem / 8 + 255) / 256), 256, 0, stream>>>(xin, ybA, nelem);
        hipMemsetAsync(cnt, 0, (size_t)Nn * 4, stream);
        count_deg<<<(E + 255) / 256, 256, 0, stream>>>(ei, E, cnt);
        scan_deg<<<1, 1024, 0, stream>>>(cnt, rowptr, Nn);
        hipMemsetAsync(cnt, 0, (size_t)Nn * 4, stream);
        fill_csr<<<(E + 255) / 256, 256, 0, stream>>>(ei, E, rowptr, cnt, csr);
        f16* yin = ybA;
        f16* yout = ybB;
        int RB = (Nn + 127) / 128;
        int RBp = (RB + 7) & ~7;
        for (int l = 0; l < 3; l++) {
            const float* Wr = (const float*)d_in[pbase + l * 5 + 0];
            const float* br = (const float*)d_in[pbase + l * 5 + 1];
            const float* Wss = (const float*)d_in[pbase + l * 5 + 2];
            const float* bg = (const float*)d_in[pbase + l * 5 + 3];
            const float* bb = (const float*)d_in[pbase + l * 5 + 4];
            transpose_tile<<<dim3(8, 8), dim3(32, 8), 0, stream>>>(Wss, WcatT, 256, 256, 0, 0, 512);
            transpose_tile<<<dim3(8, 8), dim3(32, 8), 0, stream>>>(Wr, WcatT, 256, 256, 0, 256, 512);
            agg_x<<<(Nn * 64 + 255) / 256, 256, 0, stream>>>(rowptr, csr, yin, XAbuf, Nn);
            hipMemsetAsync(stats, 0, 512 * 4, stream);
            // y = lrelu([X|XA] @ [Ws;Wr] + br), fused column stats
            gemm_f16<<<2 * RBp, 256, 0, stream>>>(nullptr, nullptr, yin, XAbuf, 0,
                                                  WcatT, br, yout, Nn, 256, 512, 1, 2, RBp,
                                                  nullptr, nullptr, stats);
            bn_apply<<<(int)((nelem / 8 + 255) / 256), 256, 0, stream>>>(
                yout, stats, bg, bb, 1.0f / Nn, wl[l], tout, nelem, l == 0);
            f16* tmp = yin; yin = yout; yout = tmp;
        }
    };

    run_tower(gene_x, g_ei, N_G, E_G, 5, gene_out);
    run_tower(disease_x, d_ei, N_D, E_D, 20, dis_out);

    const float* lin1_W = (const float*)d_in[35];
    const float* lin1_b = (const float*)d_in[36];
    const float* lin2_W = (const float*)d_in[37];
    const float* lin2_b = (const float*)d_in[38];
    const float* lin3_W = (const float*)d_in[39];
    const float* lin3_b = (const float*)d_in[40];
    const float* lin4_W = (const float*)d_in[41];
    const float* lin4_b = (const float*)d_in[42];

    transpose_tile<<<dim3(64, 16), dim3(32, 8), 0, stream>>>(lin1_W, W1T, 512, 2048, 0, 0, 512);
    transpose_tile<<<dim3(32, 64), dim3(32, 8), 0, stream>>>(lin2_W, W2T, 2048, 1024, 0, 0, 2048);
    transpose_tile<<<dim3(16, 32), dim3(32, 8), 0, stream>>>(lin3_W, W3T, 1024, 512, 0, 0, 1024);
    init_out<<<(BATCH * 2 + 255) / 256, 256, 0, stream>>>(lin4_b, out, BATCH * 2);

    for (int c = 0; c < chunks; c++) {
        int rb = c * R;
        if ((R & 255) == 0) {
            int RB2 = R / 256;
            // lin1 (gather) and lin2 on the 256x256 counted-vmcnt kernel
            gemm256<<<8 * RB2, 512, 0, stream>>>(nullptr, bidx, gene_out, dis_out, rb,
                                                 W1T, lin1_b, h1, R, 2048, 512, 1, 8, RB2);
            gemm256<<<4 * RB2, 512, 0, stream>>>(h1, nullptr, nullptr, nullptr, 0,
                                                 W2T, lin2_b, h2, R, 1024, 2048, 1, 4, RB2);
        } else {
            int RB = R / 128;
            gemm_f16<<<16 * RB, 256, 0, stream>>>(nullptr, bidx, gene_out, dis_out, rb,
                                                  W1T, lin1_b, h1, R, 2048, 512, 1, 16, RB,
                                                  nullptr, nullptr, nullptr);
            gemm_f16<<<8 * RB, 256, 0, stream>>>(h1, nullptr, nullptr, nullptr, 0,
                                                 W2T, lin2_b, h2, R, 1024, 2048, 1, 8, RB,
                                                 nullptr, nullptr, nullptr);
        }
        int RB = R / 128;
        // lin3 with fused lin4: atomics into out (fp32)
        gemm_f16<<<4 * RB, 256, 0, stream>>>(h2, nullptr, nullptr, nullptr, rb,
                                             W3T, lin3_b, nullptr, R, 512, 1024, 1, 4, RB,
                                             lin4_W, out, nullptr);
    }
}

// Round 4
// 1467.106 us; speedup vs baseline: 1.3267x; 1.0118x over previous
//
#include <hip/hip_runtime.h>
#include <hip/hip_bf16.h>
#include <cstdint>
#include <cstddef>

#define N_G 50000
#define N_D 20000
#define E_G 300000
#define E_D 150000
#define BATCH 65536

typedef _Float16 f16;
typedef _Float16 f16x8 __attribute__((ext_vector_type(8)));
typedef _Float16 f16x4 __attribute__((ext_vector_type(4)));
typedef float f32x4 __attribute__((ext_vector_type(4)));

__device__ __forceinline__ float clampf(float v) {
    return fminf(fmaxf(v, -60000.f), 60000.f);  // also squashes NaN
}

__device__ __forceinline__ void gl_lds16(const void* g, void* l) {
    __builtin_amdgcn_global_load_lds(
        (const __attribute__((address_space(1))) unsigned int*)g,
        (__attribute__((address_space(3))) unsigned int*)l, 16, 0, 0);
}

// ---------------- GEMM (128x128, 4 waves): C = act(A @ Bt^T + bias) ----------------
// Proven R7/R8 structure. Used for tower layers (N=256) and lin3(+fused lin4).
// R10: optional fused column-stats (sum, sumsq) for BN -> stats[0..255]/[256..511].
__global__ __launch_bounds__(256) void gemm_f16(
    const f16* __restrict__ A,
    const int* __restrict__ bidx,
    const f16* __restrict__ geneT, const f16* __restrict__ disT, int rowBase,
    const f16* __restrict__ Bt, const float* __restrict__ bias,
    f16* __restrict__ C, int M, int N, int K, int relu, int CB, int RB,
    const float* __restrict__ W4, float* __restrict__ outF,
    float* __restrict__ stats)
{
    alignas(16) __shared__ f16 sA[128 * 64];
    alignas(16) __shared__ f16 sB[128 * 64];
    const int t = threadIdx.x;
    const int w = t >> 6, l = t & 63;
    const int wm = w >> 1, wn = w & 1;
    const int q = l >> 4, lr = l & 15;

    int flat = blockIdx.x;
    int cb, rb;
    if ((RB & 7) == 0) {
        int x = flat & 7, idx = flat >> 3;
        int Sx = RB >> 3;
        cb = idx % CB;
        rb = x * Sx + idx / CB;
    } else {
        cb = flat % CB;
        rb = flat / CB;
    }
    const int mBase = rb * 128, nBase = cb * 128;

    const int subrow = l >> 3;   // 0..7
    const int c = l & 7;         // 16B chunk 0..7 within a 128B row
    const char* pA[4];
    const char* pD[4];
    const char* pB[4];
    const bool fused = (bidx != nullptr);
    const bool concat = (!fused && disT != nullptr);
    const bool twoSrc = fused || concat;
#pragma unroll
    for (int j = 0; j < 4; j++) {
        int seg = j * 4 + w;
        int lrow = seg * 8 + subrow;               // 0..127
        int coff = ((c ^ (lrow & 7)) << 4);        // swizzled chunk byte offset
        if (fused) {
            int rg = rowBase + mBase + lrow;       // M % 128 == 0 on this path
            int gi = bidx[2 * rg], di = bidx[2 * rg + 1];
            pA[j] = (const char*)geneT + (size_t)gi * 512 + coff;
            pD[j] = (const char*)disT + (size_t)di * 512 + coff;
        } else if (concat) {
            int arow = mBase + lrow; if (arow > M - 1) arow = M - 1;
            pA[j] = (const char*)geneT + (size_t)arow * 512 + coff;
            pD[j] = (const char*)disT + (size_t)arow * 512 + coff;
        } else {
            int arow = mBase + lrow; if (arow > M - 1) arow = M - 1;
            pA[j] = (const char*)A + (size_t)arow * K * 2 + coff;
            pD[j] = nullptr;
        }
        int brow = nBase + lrow; if (brow > N - 1) brow = N - 1;
        pB[j] = (const char*)Bt + (size_t)brow * K * 2 + coff;
    }

    f32x4 acc[4][4] = {};

    for (int k0 = 0; k0 < K; k0 += 64) {
        __syncthreads();
#pragma unroll
        for (int j = 0; j < 4; j++) {
            int seg = j * 4 + w;
            const char* srcA;
            if (twoSrc)
                srcA = (k0 < 256) ? (pA[j] + (size_t)k0 * 2) : (pD[j] + (size_t)(k0 - 256) * 2);
            else
                srcA = pA[j] + (size_t)k0 * 2;
            gl_lds16(srcA, sA + seg * 512);
            gl_lds16(pB[j] + (size_t)k0 * 2, sB + seg * 512);
        }
        __syncthreads();
        f16x8 a0[4], a1[4], b0[4], b1[4];
#pragma unroll
        for (int i = 0; i < 4; i++) {
            int r = wm * 64 + i * 16 + lr;
            int rs = r * 64;
            int x0 = (q ^ (r & 7)) << 3;
            int x1 = ((4 + q) ^ (r & 7)) << 3;
            a0[i] = *(const f16x8*)(sA + rs + x0);
            a1[i] = *(const f16x8*)(sA + rs + x1);
        }
#pragma unroll
        for (int jj = 0; jj < 4; jj++) {
            int r = wn * 64 + jj * 16 + lr;
            int rs = r * 64;
            int x0 = (q ^ (r & 7)) << 3;
            int x1 = ((4 + q) ^ (r & 7)) << 3;
            b0[jj] = *(const f16x8*)(sB + rs + x0);
            b1[jj] = *(const f16x8*)(sB + rs + x1);
        }
#pragma unroll
        for (int i = 0; i < 4; i++)
#pragma unroll
            for (int jj = 0; jj < 4; jj++) {
                acc[i][jj] = __builtin_amdgcn_mfma_f32_16x16x32_f16(a0[i], b0[jj], acc[i][jj], 0, 0, 0);
                acc[i][jj] = __builtin_amdgcn_mfma_f32_16x16x32_f16(a1[i], b1[jj], acc[i][jj], 0, 0, 0);
            }
    }

    if (W4 != nullptr) {
        // fused final linear: out[rowBase+row] += lrelu(acc + bias) @ W4 (512x2)
        float w40[4], w41[4];
#pragma unroll
        for (int j = 0; j < 4; j++) {
            int col = nBase + wn * 64 + j * 16 + lr;
            w40[j] = W4[col * 2];
            w41[j] = W4[col * 2 + 1];
        }
#pragma unroll
        for (int i = 0; i < 4; i++) {
#pragma unroll
            for (int r = 0; r < 4; r++) {
                int row = mBase + wm * 64 + i * 16 + q * 4 + r;
                float s0 = 0.f, s1 = 0.f;
#pragma unroll
                for (int j = 0; j < 4; j++) {
                    int col = nBase + wn * 64 + j * 16 + lr;
                    float v = acc[i][j][r] + bias[col];
                    v = v >= 0.f ? v : 0.01f * v;
                    v = clampf(v);
                    s0 += v * w40[j];
                    s1 += v * w41[j];
                }
#pragma unroll
                for (int off = 1; off < 16; off <<= 1) {
                    s0 += __shfl_xor(s0, off);
                    s1 += __shfl_xor(s1, off);
                }
                if (lr == 0 && row < M) {
                    atomicAdd(&outF[(size_t)(rowBase + row) * 2], s0);
                    atomicAdd(&outF[(size_t)(rowBase + row) * 2 + 1], s1);
                }
            }
        }
        return;
    }

    // ---- epilogue: per-wave LDS transpose, then coalesced f16x8 stores ----
    __syncthreads();
    f16* lt = ((w >> 1) ? sB : sA) + (w & 1) * 4096;

    float bj[4];
#pragma unroll
    for (int j = 0; j < 4; j++)
        bj[j] = bias ? bias[nBase + wn * 64 + j * 16 + lr] : 0.f;

    float sj[4] = {0.f, 0.f, 0.f, 0.f}, s2j[4] = {0.f, 0.f, 0.f, 0.f};
#pragma unroll
    for (int i = 0; i < 4; i++)
#pragma unroll
        for (int j = 0; j < 4; j++) {
            int col = j * 16 + lr;
#pragma unroll
            for (int r = 0; r < 4; r++) {
                int row = i * 16 + q * 4 + r;       // 0..63 wave-local
                float v = acc[i][j][r] + bj[j];
                if (relu) v = v >= 0.f ? v : 0.01f * v;
                v = clampf(v);
                if (stats && (mBase + wm * 64 + row) < M) { sj[j] += v; s2j[j] += v * v; }
                int cs = col ^ ((((row >> 2) & 3) << 4) ^ ((row & 3) << 3));
                lt[row * 64 + cs] = (f16)v;
            }
        }

    if (stats) {
        // reduce over q (lanes ^16, ^32 share lr), one atomic pair per column per wave
#pragma unroll
        for (int j = 0; j < 4; j++) {
            float s = sj[j], s2 = s2j[j];
            s += __shfl_xor(s, 16); s2 += __shfl_xor(s2, 16);
            s += __shfl_xor(s, 32); s2 += __shfl_xor(s2, 32);
            if (q == 0) {
                int col = nBase + wn * 64 + j * 16 + lr;
                if (col < 256 && col < N) {
                    atomicAdd(&stats[col], s);
                    atomicAdd(&stats[256 + col], s2);
                }
            }
        }
    }
    __syncthreads();

    const int rr = l >> 3;
    const int c8 = l & 7;
#pragma unroll
    for (int it = 0; it < 8; it++) {
        int row = it * 8 + rr;
        int cs = (c8 * 8) ^ ((((row >> 2) & 3) << 4) ^ ((row & 3) << 3));
        f16x8 vv = *(const f16x8*)(lt + row * 64 + cs);
        int grow = mBase + wm * 64 + row;
        if (grow < M)
            *(f16x8*)(C + (size_t)grow * N + nBase + wn * 64 + c8 * 8) = vv;
    }
}

// ---------------- GEMM 256x256, 8 waves, prefetch-distance-2 ----------------
// R11: A triple-buffered (3x32KB), B double-buffered (2x32KB) = 160 KiB LDS.
// Issue order per iter kt: stage B(kt+1), stage A(kt+2), s_waitcnt vmcnt(12)
// (= A(kt+1)+B(kt+1)+A(kt+2) outstanding; waits for A(kt),B(kt)), s_barrier,
// compute, s_barrier. A (HBM/L3: h1, gathered rows) gets ~2 iterations of
// latency cover; B (L2-resident weights) gets ~1. Tails: vmcnt(8), vmcnt(0).
__global__ __launch_bounds__(512) void gemm256(
    const f16* __restrict__ A,
    const int* __restrict__ bidx,
    const f16* __restrict__ geneT, const f16* __restrict__ disT, int rowBase,
    const f16* __restrict__ Bt, const float* __restrict__ bias,
    f16* __restrict__ C, int M, int N, int K, int relu, int CB, int RB)
{
    alignas(16) __shared__ f16 sm[81920];   // A: 3x16384 | B: 2x16384 (f16 units)
    const int t = threadIdx.x;
    const int w = t >> 6, l = t & 63;
    const int wm = w >> 2, wn = w & 3;      // 2 x 4 wave grid
    const int q = l >> 4, lr = l & 15;

    int flat = blockIdx.x;
    int cb, rb;
    if ((RB & 7) == 0) {
        int x = flat & 7, idx = flat >> 3;
        int Sx = RB >> 3;
        cb = idx % CB;
        rb = x * Sx + idx / CB;
    } else {
        cb = flat % CB;
        rb = flat / CB;
    }
    const int mBase = rb * 256, nBase = cb * 256;

    const int subrow = l >> 3;   // 0..7
    const int c = l & 7;         // 16B chunk within a 128B row
    const bool gat = (bidx != nullptr);
    const char* pA[4];
    const char* pD[4];
    const char* pB[4];
#pragma unroll
    for (int jj = 0; jj < 4; jj++) {
        int arow = jj * 64 + w * 8 + subrow;        // 0..255 tile-local row
        int coff = ((c ^ (arow & 7)) << 4);         // inverse-swizzled source chunk
        if (gat) {
            int rg = rowBase + mBase + arow;        // M % 256 == 0 on this path
            int gi = bidx[2 * rg], di = bidx[2 * rg + 1];
            pA[jj] = (const char*)geneT + (size_t)gi * 512 + coff;
            pD[jj] = (const char*)disT + (size_t)di * 512 + coff;
        } else {
            int ga = mBase + arow; if (ga > M - 1) ga = M - 1;
            pA[jj] = (const char*)A + (size_t)ga * K * 2 + coff;
            pD[jj] = nullptr;
        }
        int gb = nBase + arow; if (gb > N - 1) gb = N - 1;
        pB[jj] = (const char*)Bt + (size_t)gb * K * 2 + coff;
    }

    f16* const smA = sm;                // 3 bufs
    f16* const smB = sm + 3 * 16384;    // 2 bufs

    auto stageA = [&](int abuf, int k0) {
        f16* bA = smA + abuf * 16384;
#pragma unroll
        for (int jj = 0; jj < 4; jj++) {
            int R0 = jj * 64 + w * 8;               // wave-uniform LDS row base
            const char* srcA;
            if (gat)
                srcA = (k0 < 256) ? (pA[jj] + (size_t)k0 * 2) : (pD[jj] + (size_t)(k0 - 256) * 2);
            else
                srcA = pA[jj] + (size_t)k0 * 2;
            gl_lds16(srcA, bA + R0 * 64);
        }
    };
    auto stageB = [&](int bbuf, int k0) {
        f16* bB = smB + bbuf * 16384;
#pragma unroll
        for (int jj = 0; jj < 4; jj++) {
            int R0 = jj * 64 + w * 8;
            gl_lds16(pB[jj] + (size_t)k0 * 2, bB + R0 * 64);
        }
    };

    f32x4 acc[8][4] = {};
    const int nkt = K >> 6;

    // prologue: A(0), B(0), A(1)
    stageA(0, 0);
    stageB(0, 0);
    if (nkt > 1) stageA(1, 64);

    for (int kt = 0; kt < nkt; kt++) {
        if (kt + 1 < nkt) stageB((kt + 1) & 1, (kt + 1) << 6);
        if (kt + 2 < nkt) stageA((kt + 2) % 3, (kt + 2) << 6);
        if (kt + 2 < nkt)      asm volatile("s_waitcnt vmcnt(12)" ::: "memory");
        else if (kt + 1 < nkt) asm volatile("s_waitcnt vmcnt(8)" ::: "memory");
        else                   asm volatile("s_waitcnt vmcnt(0)" ::: "memory");
        __builtin_amdgcn_s_barrier();
        __builtin_amdgcn_sched_barrier(0);
        const f16* bA = smA + (kt % 3) * 16384;
        const f16* bB = smB + (kt & 1) * 16384;
#pragma unroll
        for (int ks = 0; ks < 2; ks++) {
            f16x8 bf[4];
#pragma unroll
            for (int nf = 0; nf < 4; nf++) {
                int rB = wn * 64 + nf * 16 + lr;
                bf[nf] = *(const f16x8*)(bB + rB * 64 + ((((ks << 2) + q) ^ (rB & 7)) << 3));
            }
#pragma unroll
            for (int mf = 0; mf < 8; mf++) {
                int rA = wm * 128 + mf * 16 + lr;
                f16x8 af = *(const f16x8*)(bA + rA * 64 + ((((ks << 2) + q) ^ (rA & 7)) << 3));
#pragma unroll
                for (int nf = 0; nf < 4; nf++)
                    acc[mf][nf] = __builtin_amdgcn_mfma_f32_16x16x32_f16(af, bf[nf], acc[mf][nf], 0, 0, 0);
            }
        }
        __builtin_amdgcn_sched_barrier(0);
        __builtin_amdgcn_s_barrier();
    }
    __builtin_amdgcn_sched_barrier(0);

    // ---- epilogue: per-wave 128x64 LDS transpose (16KB slice), f16x8 stores ----
    f16* lt = sm + w * 8192;
    float bj[4];
#pragma unroll
    for (int nf = 0; nf < 4; nf++)
        bj[nf] = bias ? bias[nBase + wn * 64 + nf * 16 + lr] : 0.f;

#pragma unroll
    for (int mf = 0; mf < 8; mf++)
#pragma unroll
        for (int nf = 0; nf < 4; nf++) {
            int col = nf * 16 + lr;
#pragma unroll
            for (int r = 0; r < 4; r++) {
                int row = mf * 16 + q * 4 + r;      // 0..127 wave-local
                float v = acc[mf][nf][r] + bj[nf];
                if (relu) v = v >= 0.f ? v : 0.01f * v;
                v = clampf(v);
                int cs = col ^ ((((row >> 2) & 3) << 4) ^ ((row & 3) << 3));
                lt[row * 64 + cs] = (f16)v;
            }
        }

    const int rr = l >> 3;
    const int c8 = l & 7;
#pragma unroll
    for (int it = 0; it < 16; it++) {
        int row = it * 8 + rr;                      // 0..127 wave-local
        int cs = (c8 * 8) ^ ((((row >> 2) & 3) << 4) ^ ((row & 3) << 3));
        f16x8 vv = *(const f16x8*)(lt + row * 64 + cs);
        int grow = mBase + wm * 128 + row;
        if (grow < M)
            *(f16x8*)(C + (size_t)grow * N + nBase + wn * 64 + c8 * 8) = vv;
    }
}

// ---------------- small kernels ----------------
__global__ void cvt_f32_f16(const float* __restrict__ in, f16* __restrict__ out, size_t n) {
    size_t i = ((size_t)blockIdx.x * 256 + threadIdx.x) * 8;
    if (i >= n) return;
    f32x4 a = *(const f32x4*)(in + i);
    f32x4 b = *(const f32x4*)(in + i + 4);
    f16x8 o;
    o[0] = (f16)clampf(a.x); o[1] = (f16)clampf(a.y);
    o[2] = (f16)clampf(a.z); o[3] = (f16)clampf(a.w);
    o[4] = (f16)clampf(b.x); o[5] = (f16)clampf(b.y);
    o[6] = (f16)clampf(b.z); o[7] = (f16)clampf(b.w);
    *(f16x8*)(out + i) = o;
}

__global__ void init_out(const float* __restrict__ b4, float* __restrict__ out, int n) {
    int i = blockIdx.x * 256 + threadIdx.x;
    if (i < n) out[i] = b4[i & 1];
}

__global__ void count_deg(const int* __restrict__ ei, int E, int* __restrict__ deg) {
    int e = blockIdx.x * 256 + threadIdx.x;
    if (e < E) atomicAdd(&deg[ei[E + e]], 1);
}

__global__ void scan_deg(const int* __restrict__ deg, int* __restrict__ rowptr, int Nn) {
    __shared__ int part[1024];
    const int t = threadIdx.x;
    const int C = (Nn + 1023) >> 10;
    const int base = t * C;
    int s = 0;
    for (int i = 0; i < C; i++) { int idx = base + i; if (idx < Nn) s += deg[idx]; }
    part[t] = s;
    __syncthreads();
    for (int off = 1; off < 1024; off <<= 1) {
        int v = (t >= off) ? part[t - off] : 0;
        __syncthreads();
        part[t] += v;
        __syncthreads();
    }
    int pre = (t == 0) ? 0 : part[t - 1];
    for (int i = 0; i < C; i++) {
        int idx = base + i;
        if (idx < Nn) { rowptr[idx] = pre; pre += deg[idx]; }
    }
    if (t == 1023) rowptr[Nn] = part[1023];
}

__global__ void fill_csr(const int* __restrict__ ei, int E, const int* __restrict__ rowptr,
                         int* __restrict__ cursor, int* __restrict__ csr) {
    int e = blockIdx.x * 256 + threadIdx.x;
    if (e < E) {
        int d = ei[E + e];
        int p = rowptr[d] + atomicAdd(&cursor[d], 1);
        csr[p] = ei[e];
    }
}

// pre-aggregation (GraphConv linearity): XA[i] = sum_{j->i} X[j]
__global__ void agg_x(const int* __restrict__ rowptr, const int* __restrict__ csr,
                      const f16* __restrict__ X, f16* __restrict__ XA, int Nn) {
    int gid = blockIdx.x * 256 + threadIdx.x;
    int node = gid >> 6, l = gid & 63;
    if (node >= Nn) return;
    int beg = rowptr[node], end = rowptr[node + 1];
    float s0 = 0.f, s1 = 0.f, s2 = 0.f, s3 = 0.f;
    for (int e = beg; e < end; e++) {
        int src = csr[e];
        f16x4 xv = *(const f16x4*)(X + (size_t)src * 256 + l * 4);
        s0 += (float)xv.x; s1 += (float)xv.y; s2 += (float)xv.z; s3 += (float)xv.w;
    }
    f16x4 o;
    o.x = (f16)clampf(s0); o.y = (f16)clampf(s1);
    o.z = (f16)clampf(s2); o.w = (f16)clampf(s3);
    *(f16x4*)(XA + (size_t)node * 256 + l * 4) = o;
}

// Tiled transpose: WT[(dstRowOff+n)*LK + dstColOff + k] = W[k][n]
__global__ void transpose_tile(const float* __restrict__ W, f16* __restrict__ WT,
                               int K, int N, int dstRowOff, int dstColOff, int LK) {
    __shared__ float tile[32][33];
    int n0 = blockIdx.x * 32, k0 = blockIdx.y * 32;
    int tx = threadIdx.x, ty = threadIdx.y;
    for (int yy = ty; yy < 32; yy += 8) {
        int k = k0 + yy, n = n0 + tx;
        tile[yy][tx] = (k < K && n < N) ? W[(size_t)k * N + n] : 0.f;
    }
    __syncthreads();
    for (int yy = ty; yy < 32; yy += 8) {
        int n = n0 + yy, k = k0 + tx;
        if (n < N && k < K)
            WT[(size_t)(dstRowOff + n) * LK + dstColOff + k] = (f16)clampf(tile[tx][yy]);
    }
}

// BN on y; acc (f16, persistent) = (initAcc ? 0 : acc) + w * BN(y).  Vectorized x8.
__global__ void bn_apply(f16* __restrict__ y, const float* __restrict__ stats,
                         const float* __restrict__ g, const float* __restrict__ b,
                         float invN, float w, f16* __restrict__ acc, size_t total,
                         int initAcc) {
    size_t i = ((size_t)blockIdx.x * 256 + threadIdx.x) * 8;
    if (i >= total) return;
    int colb = (int)(i & 255);
    f16x8 yv = *(const f16x8*)(y + i);
    f16x8 av = {};
    if (!initAcc) av = *(const f16x8*)(acc + i);
    f16x8 yo, ao;
#pragma unroll
    for (int j = 0; j < 8; j++) {
        int col = colb + j;
        float m = stats[col] * invN;
        float var = stats[256 + col] * invN - m * m;
        if (var < 0.f) var = 0.f;
        float rs = 1.0f / sqrtf(var + 1e-5f);
        float v = ((float)yv[j] - m) * rs * g[col] + b[col];
        v = clampf(v);
        yo[j] = (f16)v;
        float p = initAcc ? 0.f : (float)av[j];
        ao[j] = (f16)clampf(p + w * v);
    }
    *(f16x8*)(y + i) = yo;
    *(f16x8*)(acc + i) = ao;
}

extern "C" void kernel_launch(void* const* d_in, const int* in_sizes, int n_in,
                              void* d_out, int out_size, void* d_ws, size_t ws_size,
                              hipStream_t stream) {
    char* ws = (char*)d_ws;
    size_t off = 0;
    auto alloc = [&](size_t bytes) -> void* {
        void* p = ws + off;
        off += (bytes + 255) & ~(size_t)255;
        return p;
    };

    // persistent (~45 MB)
    f16* gene_out = (f16*)alloc((size_t)N_G * 256 * 2);
    f16* dis_out  = (f16*)alloc((size_t)N_D * 256 * 2);
    f16* W1T = (f16*)alloc((size_t)2048 * 512 * 2);
    f16* W2T = (f16*)alloc((size_t)1024 * 2048 * 2);
    f16* W3T = (f16*)alloc((size_t)512 * 1024 * 2);
    f16* WcatT = (f16*)alloc((size_t)256 * 512 * 2);
    int* csr = (int*)alloc((size_t)E_G * 4);
    int* rowptr = (int*)alloc((size_t)(N_G + 1) * 4);
    int* cnt = (int*)alloc((size_t)N_G * 4);
    float* stats = (float*)alloc(512 * 4);

    char* scratch = ws + off;
    size_t avail = (ws_size > off) ? (ws_size - off) : 0;

    f16* ybA = (f16*)scratch;
    f16* ybB = ybA + (size_t)N_G * 256;
    f16* XAbuf = ybB + (size_t)N_G * 256;

    // head chunk: R rows use R*6144 bytes (h1 4KB + h2 2KB per row)
    int R = 32768;
    while ((size_t)R * 6144 > avail && R > 256) R >>= 1;
    int chunks = BATCH / R;
    f16* h1 = (f16*)scratch;
    f16* h2 = h1 + (size_t)R * 2048;

    const float* gene_x = (const float*)d_in[0];
    const float* disease_x = (const float*)d_in[1];
    const int* g_ei = (const int*)d_in[2];
    const int* d_ei = (const int*)d_in[3];
    const int* bidx = (const int*)d_in[4];
    float* out = (float*)d_out;

    const float wl[3] = {0.7f, 0.2f, 0.1f};

    auto run_tower = [&](const float* xin, const int* ei, int Nn, int E, int pbase, f16* tout) {
        size_t nelem = (size_t)Nn * 256;
        cvt_f32_f16<<<(int)((nelem / 8 + 255) / 256), 256, 0, stream>>>(xin, ybA, nelem);
        hipMemsetAsync(cnt, 0, (size_t)Nn * 4, stream);
        count_deg<<<(E + 255) / 256, 256, 0, stream>>>(ei, E, cnt);
        scan_deg<<<1, 1024, 0, stream>>>(cnt, rowptr, Nn);
        hipMemsetAsync(cnt, 0, (size_t)Nn * 4, stream);
        fill_csr<<<(E + 255) / 256, 256, 0, stream>>>(ei, E, rowptr, cnt, csr);
        f16* yin = ybA;
        f16* yout = ybB;
        int RB = (Nn + 127) / 128;
        int RBp = (RB + 7) & ~7;
        for (int l = 0; l < 3; l++) {
            const float* Wr = (const float*)d_in[pbase + l * 5 + 0];
            const float* br = (const float*)d_in[pbase + l * 5 + 1];
            const float* Wss = (const float*)d_in[pbase + l * 5 + 2];
            const float* bg = (const float*)d_in[pbase + l * 5 + 3];
            const float* bb = (const float*)d_in[pbase + l * 5 + 4];
            transpose_tile<<<dim3(8, 8), dim3(32, 8), 0, stream>>>(Wss, WcatT, 256, 256, 0, 0, 512);
            transpose_tile<<<dim3(8, 8), dim3(32, 8), 0, stream>>>(Wr, WcatT, 256, 256, 0, 256, 512);
            agg_x<<<(Nn * 64 + 255) / 256, 256, 0, stream>>>(rowptr, csr, yin, XAbuf, Nn);
            hipMemsetAsync(stats, 0, 512 * 4, stream);
            // y = lrelu([X|XA] @ [Ws;Wr] + br), fused column stats
            gemm_f16<<<2 * RBp, 256, 0, stream>>>(nullptr, nullptr, yin, XAbuf, 0,
                                                  WcatT, br, yout, Nn, 256, 512, 1, 2, RBp,
                                                  nullptr, nullptr, stats);
            bn_apply<<<(int)((nelem / 8 + 255) / 256), 256, 0, stream>>>(
                yout, stats, bg, bb, 1.0f / Nn, wl[l], tout, nelem, l == 0);
            f16* tmp = yin; yin = yout; yout = tmp;
        }
    };

    run_tower(gene_x, g_ei, N_G, E_G, 5, gene_out);
    run_tower(disease_x, d_ei, N_D, E_D, 20, dis_out);

    const float* lin1_W = (const float*)d_in[35];
    const float* lin1_b = (const float*)d_in[36];
    const float* lin2_W = (const float*)d_in[37];
    const float* lin2_b = (const float*)d_in[38];
    const float* lin3_W = (const float*)d_in[39];
    const float* lin3_b = (const float*)d_in[40];
    const float* lin4_W = (const float*)d_in[41];
    const float* lin4_b = (const float*)d_in[42];

    transpose_tile<<<dim3(64, 16), dim3(32, 8), 0, stream>>>(lin1_W, W1T, 512, 2048, 0, 0, 512);
    transpose_tile<<<dim3(32, 64), dim3(32, 8), 0, stream>>>(lin2_W, W2T, 2048, 1024, 0, 0, 2048);
    transpose_tile<<<dim3(16, 32), dim3(32, 8), 0, stream>>>(lin3_W, W3T, 1024, 512, 0, 0, 1024);
    init_out<<<(BATCH * 2 + 255) / 256, 256, 0, stream>>>(lin4_b, out, BATCH * 2);

    for (int c = 0; c < chunks; c++) {
        int rb = c * R;
        if ((R & 255) == 0) {
            int RB2 = R / 256;
            // lin1 (gather) and lin2 on the 256x256 prefetch-2 kernel
            gemm256<<<8 * RB2, 512, 0, stream>>>(nullptr, bidx, gene_out, dis_out, rb,
                                                 W1T, lin1_b, h1, R, 2048, 512, 1, 8, RB2);
            gemm256<<<4 * RB2, 512, 0, stream>>>(h1, nullptr, nullptr, nullptr, 0,
                                                 W2T, lin2_b, h2, R, 1024, 2048, 1, 4, RB2);
        } else {
            int RB = R / 128;
            gemm_f16<<<16 * RB, 256, 0, stream>>>(nullptr, bidx, gene_out, dis_out, rb,
                                                  W1T, lin1_b, h1, R, 2048, 512, 1, 16, RB,
                                                  nullptr, nullptr, nullptr);
            gemm_f16<<<8 * RB, 256, 0, stream>>>(h1, nullptr, nullptr, nullptr, 0,
                                                 W2T, lin2_b, h2, R, 1024, 2048, 1, 8, RB,
                                                 nullptr, nullptr, nullptr);
        }
        int RB = R / 128;
        // lin3 with fused lin4: atomics into out (fp32)
        gemm_f16<<<4 * RB, 256, 0, stream>>>(h2, nullptr, nullptr, nullptr, rb,
                                             W3T, lin3_b, nullptr, R, 512, 1024, 1, 4, RB,
                                             lin4_W, out, nullptr);
    }
}